// Round 1
// 694.861 us; speedup vs baseline: 1.9995x; 1.9995x over previous
//
#include <hip/hip_runtime.h>
#include <hip/hip_bf16.h>
#include <cstddef>

// Problem constants
#define LL 1024
#define DD0 256
#define NDIR 6
#define NL 2
#define HH 8
#define PP 64
#define NN 32
#define KK 4
#define DI 512           // 2*D
#define DIN 1096         // 2*DI + 2*N + H
#define CONV_DIM 576     // DI + 2*N

// chunked scan config
#define QC 64            // chunk length
#define NC 16            // LL / QC

__constant__ int c_ord[6][3] = {{0,1,2},{0,2,1},{1,0,2},{1,2,0},{2,0,1},{2,1,0}};

// ---------------- helpers ----------------
__device__ inline float blockReduceSum256(float v) {
    __shared__ float sred[4];
#pragma unroll
    for (int off = 1; off < 64; off <<= 1) v += __shfl_xor(v, off);
    int lane = threadIdx.x & 63, w = threadIdx.x >> 6;
    __syncthreads();               // protect sred from a previous call
    if (lane == 0) sred[w] = v;
    __syncthreads();
    return sred[0] + sred[1] + sred[2] + sred[3];
}

__device__ inline float siluf(float x) { return x / (1.f + expf(-x)); }

// ---------------- sort (lexsort via rank counting) ----------------
__global__ __launch_bounds__(1024)
void sort_kernel(const int* __restrict__ coords, int* __restrict__ perm, int* __restrict__ rank) {
    int d = blockIdx.x;
    int i = threadIdx.x;
    __shared__ unsigned keys[LL];
    int a0 = c_ord[d][0], a1 = c_ord[d][1], a2 = c_ord[d][2];
    unsigned c0 = (unsigned)coords[i*4 + a0];
    unsigned c1 = (unsigned)coords[i*4 + a1];
    unsigned c2 = (unsigned)coords[i*4 + a2];
    unsigned key = (c0 << 22) | (c1 << 16) | (c2 << 10) | (unsigned)i;
    keys[i] = key;
    __syncthreads();
    int r = 0;
    for (int j = 0; j < LL; ++j) r += (keys[j] < key) ? 1 : 0;
    perm[d*LL + r] = i;
    rank[d*LL + i] = r;
}

// ---------------- gather x = vectors[perm] ----------------
__global__ __launch_bounds__(256)
void gather_kernel(const float* __restrict__ vectors, const int* __restrict__ perm,
                   float* __restrict__ x) {
    int t = blockIdx.x, d = blockIdx.y, c = threadIdx.x;
    int src = perm[d*LL + t];
    x[((size_t)d*LL + t)*DD0 + c] = vectors[(size_t)src*DD0 + c];
}

// ---------------- layernorm (generic row length) ----------------
__global__ __launch_bounds__(256)
void ln_kernel(const float* __restrict__ X, float* __restrict__ Y,
               const float* __restrict__ g, const float* __restrict__ b,
               int dd, int rowsPerDir, int gstride) {
    int t = blockIdx.x, d = blockIdx.y;
    const float* xr = X + ((size_t)d*rowsPerDir + t)*dd;
    float* yr = Y + ((size_t)d*rowsPerDir + t)*dd;
    const float* gr = g + (size_t)d*gstride;
    const float* br = b + (size_t)d*gstride;
    float v[6];
    float s = 0.f, s2 = 0.f;
    int cnt = 0;
    for (int c = threadIdx.x; c < dd; c += 256) {
        float xv = xr[c];
        v[cnt++] = xv;
        s += xv; s2 += xv*xv;
    }
    float tot = blockReduceSum256(s);
    float tot2 = blockReduceSum256(s2);
    float mu = tot / dd;
    float var = tot2 / dd - mu*mu;
    float inv = rsqrtf(var + 1e-5f);
    cnt = 0;
    for (int c = threadIdx.x; c < dd; c += 256) {
        yr[c] = (v[cnt++] - mu) * inv * gr[c] + br[c];
    }
}

// ---------------- tiled fp32 GEMM, 64x64 tile, K-step 16 ----------------
// MODE 0: C = A@B ; MODE 1: C += A@B ; MODE 2: C = gelu(A@B + bias)
template<int MODE>
__global__ __launch_bounds__(256)
void gemm_tile(const float* __restrict__ Ab, const float* __restrict__ Bb,
               float* __restrict__ Cb, int M, int N, int K,
               size_t sA, size_t sB, size_t sC, const float* __restrict__ bias) {
    const float* A = Ab + (size_t)blockIdx.z * sA;
    const float* B = Bb + (size_t)blockIdx.z * sB;
    float* C = Cb + (size_t)blockIdx.z * sC;
    int row0 = blockIdx.y * 64;
    int col0 = blockIdx.x * 64;
    int tid = threadIdx.x;
    __shared__ float As[16][65];
    __shared__ float Bs[16][65];
    int tx = tid & 15, ty = tid >> 4;
    float acc[4][4] = {};
    for (int k0 = 0; k0 < K; k0 += 16) {
#pragma unroll
        for (int i = 0; i < 4; ++i) {
            int idx = i*256 + tid;
            int kk = idx & 15, r = idx >> 4;
            As[kk][r] = A[(size_t)(row0 + r)*K + k0 + kk];
        }
#pragma unroll
        for (int i = 0; i < 4; ++i) {
            int idx = i*256 + tid;
            int c = idx & 63, kk = idx >> 6;
            int col = col0 + c;
            Bs[kk][c] = (col < N) ? B[(size_t)(k0 + kk)*N + col] : 0.f;
        }
        __syncthreads();
#pragma unroll
        for (int kk = 0; kk < 16; ++kk) {
            float a[4], b[4];
#pragma unroll
            for (int m = 0; m < 4; ++m) a[m] = As[kk][ty + 16*m];
#pragma unroll
            for (int n = 0; n < 4; ++n) b[n] = Bs[kk][tx + 16*n];
#pragma unroll
            for (int m = 0; m < 4; ++m)
#pragma unroll
                for (int n = 0; n < 4; ++n) acc[m][n] = fmaf(a[m], b[n], acc[m][n]);
        }
        __syncthreads();
    }
#pragma unroll
    for (int m = 0; m < 4; ++m) {
        int r = row0 + ty + 16*m;
#pragma unroll
        for (int n = 0; n < 4; ++n) {
            int c = col0 + tx + 16*n;
            if (c < N) {
                size_t o = (size_t)r*N + c;
                if (MODE == 0) C[o] = acc[m][n];
                else if (MODE == 1) C[o] += acc[m][n];
                else {
                    float vv = acc[m][n] + bias[c];
                    C[o] = 0.5f * vv * (1.f + erff(vv * 0.70710678118654752f));
                }
            }
        }
    }
}

// ---------------- causal depthwise conv (K=4) + silu, and dt/dA ----------------
__global__ __launch_bounds__(256)
void conv_kernel(const float* __restrict__ zx, const float* __restrict__ conv_w,
                 const float* __restrict__ conv_b, const float* __restrict__ dt_bias,
                 const float* __restrict__ A_log, float* __restrict__ xc,
                 float* __restrict__ dt, float* __restrict__ dA, int layer) {
    int t = blockIdx.x, d = blockIdx.y;
    const float* Z = zx + ((size_t)d*LL)*DIN;
    const float* w = conv_w + (size_t)(d*NL + layer)*CONV_DIM*KK;
    const float* b = conv_b + (size_t)(d*NL + layer)*CONV_DIM;
    float* outr = xc + ((size_t)d*LL + t)*CONV_DIM;
    for (int c = threadIdx.x; c < CONV_DIM; c += 256) {
        float acc = b[c];
#pragma unroll
        for (int j = 0; j < KK; ++j) {
            int tt = t - (KK-1) + j;
            if (tt >= 0) acc += Z[(size_t)tt*DIN + DI + c] * w[c*KK + j];
        }
        outr[c] = siluf(acc);
    }
    if (threadIdx.x < HH) {
        int hh = threadIdx.x;
        float v = Z[(size_t)t*DIN + (DIN - HH) + hh] + dt_bias[(d*NL + layer)*HH + hh];
        float sp = (v > 20.f) ? v : log1pf(expf(v));
        dt[((size_t)d*LL + t)*HH + hh] = sp;
        dA[((size_t)d*LL + t)*HH + hh] = expf(-expf(A_log[(d*NL + layer)*HH + hh]) * sp);
    }
}

// ---------------- chunked selective scan ----------------
// The recurrence h[t] = dA[t]*h[t-1] + dt[t]*x[t]*B[t] is linear, so we
// split L into NC chunks of QC steps:
//   pass1: per-chunk local scan from h=0 (grid NDIR*H*NC -> 16x parallelism),
//          writes local y, chunk-final state, and running decay cumdec[t].
//   pass2: tiny sequential fixup over NC chunk states -> chunk-initial states.
//   pass3: y[t] += cumdec[t] * (C[t] . h_init[chunk]).
// Exact reassociation of the original scan.

// pass1: block = (d, h, chunk); 256 threads = 64 p * 4 n-groups of 8
__global__ __launch_bounds__(256)
void scan_pass1(const float* __restrict__ xc, const float* __restrict__ dtA,
                const float* __restrict__ dAA, float* __restrict__ ys,
                float* __restrict__ cstate, float* __restrict__ cumdec) {
    int bid = blockIdx.x;
    int c = bid & (NC - 1);
    int hd = bid >> 4;           // log2(NC)=4
    int d = hd >> 3, h = hd & 7;
    int tid = threadIdx.x;
    int p = tid >> 2, g = tid & 3, n0 = g << 3;
    int t0 = c * QC;
    const float* xcd = xc + (size_t)d*LL*CONV_DIM;
    const float* dtd = dtA + (size_t)d*LL*HH + h;
    const float* dAd = dAA + (size_t)d*LL*HH + h;
    float* ysd = ys + (size_t)d*LL*DI + h*PP + p;
    float* cdd = cumdec + (size_t)d*LL*HH + h;

    __shared__ float sdt[QC];
    __shared__ float sdA[QC];
    if (tid < QC) sdt[tid] = dtd[(size_t)(t0 + tid)*HH];
    else if (tid < 2*QC) sdA[tid - QC] = dAd[(size_t)(t0 + tid - QC)*HH];
    __syncthreads();

    float hs[8];
#pragma unroll
    for (int j = 0; j < 8; ++j) hs[j] = 0.f;
    float cum = 1.f;

    // prefetch first row of chunk
    const float* row = xcd + (size_t)t0*CONV_DIM;
    float xv = row[h*PP + p];
    float4 b0 = *(const float4*)(row + DI + n0);
    float4 b1 = *(const float4*)(row + DI + n0 + 4);
    float4 c0 = *(const float4*)(row + DI + NN + n0);
    float4 c1 = *(const float4*)(row + DI + NN + n0 + 4);

    for (int tt = 0; tt < QC; ++tt) {
        float nxv = 0.f;
        float4 nb0 = {0,0,0,0}, nb1 = {0,0,0,0}, nc0 = {0,0,0,0}, nc1 = {0,0,0,0};
        if (tt + 1 < QC) {
            const float* r2 = xcd + (size_t)(t0 + tt + 1)*CONV_DIM;
            nxv = r2[h*PP + p];
            nb0 = *(const float4*)(r2 + DI + n0);
            nb1 = *(const float4*)(r2 + DI + n0 + 4);
            nc0 = *(const float4*)(r2 + DI + NN + n0);
            nc1 = *(const float4*)(r2 + DI + NN + n0 + 4);
        }
        float dtv = sdt[tt], dAv = sdA[tt];
        float dtx = dtv * xv;
        float B[8] = {b0.x,b0.y,b0.z,b0.w,b1.x,b1.y,b1.z,b1.w};
        float Cv[8] = {c0.x,c0.y,c0.z,c0.w,c1.x,c1.y,c1.z,c1.w};
        float acc = 0.f;
#pragma unroll
        for (int j = 0; j < 8; ++j) {
            hs[j] = fmaf(dAv, hs[j], dtx * B[j]);
            acc = fmaf(hs[j], Cv[j], acc);
        }
        acc += __shfl_xor(acc, 1);
        acc += __shfl_xor(acc, 2);
        if (g == 0) ysd[(size_t)(t0 + tt)*DI] = acc;
        cum *= dAv;
        if (tid == 0) cdd[(size_t)(t0 + tt)*HH] = cum;
        xv = nxv; b0 = nb0; b1 = nb1; c0 = nc0; c1 = nc1;
    }

    // store chunk-final state
    float* cs = cstate + (((size_t)(d*NC + c)*HH + h)*PP + p)*NN + n0;
    float4 s0 = {hs[0], hs[1], hs[2], hs[3]};
    float4 s1 = {hs[4], hs[5], hs[6], hs[7]};
    *(float4*)cs = s0;
    *(float4*)(cs + 4) = s1;
}

// pass2: block = (d, h); sequential over NC chunks; converts chunk-final
// states to chunk-initial states in place.
__global__ __launch_bounds__(256)
void scan_pass2(float* __restrict__ cstate, const float* __restrict__ cumdec) {
    int hd = blockIdx.x;
    int d = hd >> 3, h = hd & 7;
    int tid = threadIdx.x;
    int p = tid >> 2, g = tid & 3, n0 = g << 3;
    float carry[8];
#pragma unroll
    for (int j = 0; j < 8; ++j) carry[j] = 0.f;
    for (int c = 0; c < NC; ++c) {
        float* cs = cstate + (((size_t)(d*NC + c)*HH + h)*PP + p)*NN + n0;
        float4 s0 = *(const float4*)cs;
        float4 s1 = *(const float4*)(cs + 4);
        float4 w0 = {carry[0], carry[1], carry[2], carry[3]};
        float4 w1 = {carry[4], carry[5], carry[6], carry[7]};
        *(float4*)cs = w0;
        *(float4*)(cs + 4) = w1;
        float dec = cumdec[((size_t)d*LL + (c*QC + QC - 1))*HH + h];
        float s[8] = {s0.x,s0.y,s0.z,s0.w,s1.x,s1.y,s1.z,s1.w};
#pragma unroll
        for (int j = 0; j < 8; ++j) carry[j] = fmaf(dec, carry[j], s[j]);
    }
}

// pass3: block = (d, h, chunk); y[t] += cumdec[t] * (C[t] . h_init)
__global__ __launch_bounds__(256)
void scan_pass3(const float* __restrict__ xc, const float* __restrict__ cumdec,
                const float* __restrict__ cstate, float* __restrict__ ys) {
    int bid = blockIdx.x;
    int c = bid & (NC - 1);
    if (c == 0) return;   // h_init = 0 for the first chunk
    int hd = bid >> 4;
    int d = hd >> 3, h = hd & 7;
    int tid = threadIdx.x;
    int p = tid >> 2, g = tid & 3, n0 = g << 3;
    int t0 = c * QC;

    __shared__ float scd[QC];
    if (tid < QC) scd[tid] = cumdec[((size_t)d*LL + t0 + tid)*HH + h];

    const float* cs = cstate + (((size_t)(d*NC + c)*HH + h)*PP + p)*NN + n0;
    float4 h0 = *(const float4*)cs;
    float4 h1 = *(const float4*)(cs + 4);
    float hi[8] = {h0.x,h0.y,h0.z,h0.w,h1.x,h1.y,h1.z,h1.w};
    __syncthreads();

    const float* xcd = xc + (size_t)d*LL*CONV_DIM;
    float* ysd = ys + (size_t)d*LL*DI + h*PP + p;

    for (int tt = 0; tt < QC; ++tt) {
        int t = t0 + tt;
        const float* row = xcd + (size_t)t*CONV_DIM + DI + NN;
        float4 c0 = *(const float4*)(row + n0);
        float4 c1 = *(const float4*)(row + n0 + 4);
        float Cv[8] = {c0.x,c0.y,c0.z,c0.w,c1.x,c1.y,c1.z,c1.w};
        float acc = 0.f;
#pragma unroll
        for (int j = 0; j < 8; ++j) acc = fmaf(hi[j], Cv[j], acc);
        acc += __shfl_xor(acc, 1);
        acc += __shfl_xor(acc, 2);
        if (g == 0) ysd[(size_t)t*DI] += scd[tt] * acc;
    }
}

// ---------------- gating + RMSNorm ----------------
__global__ __launch_bounds__(256)
void gate_rms(const float* __restrict__ ys, const float* __restrict__ xc,
              const float* __restrict__ zx, const float* __restrict__ Dp,
              const float* __restrict__ rms_g, float* __restrict__ u, int layer) {
    int t = blockIdx.x, d = blockIdx.y;
    const float* ysr = ys + ((size_t)d*LL + t)*DI;
    const float* xcr = xc + ((size_t)d*LL + t)*CONV_DIM;
    const float* zr = zx + ((size_t)d*LL + t)*DIN;  // z = first DI cols
    const float* Dpd = Dp + (d*NL + layer)*HH;
    const float* rg = rms_g + (size_t)(d*NL + layer)*DI;
    float* ur = u + ((size_t)d*LL + t)*DI;
    float vals[2];
    float ss = 0.f;
#pragma unroll
    for (int i = 0; i < 2; ++i) {
        int c = threadIdx.x + i*256;
        float xsv = xcr[c];
        int hh = c >> 6;
        float yv = ysr[c] + Dpd[hh] * xsv;
        float zv = zr[c];
        float uv = yv * siluf(zv);
        vals[i] = uv;
        ss += uv * uv;
    }
    float tot = blockReduceSum256(ss);
    float scale = rsqrtf(tot / DI + 1e-5f);
#pragma unroll
    for (int i = 0; i < 2; ++i) {
        int c = threadIdx.x + i*256;
        ur[c] = vals[i] * scale * rg[c];
    }
}

// ---------------- concat (inverse permute + pack) ----------------
__global__ __launch_bounds__(256)
void concat_kernel(const float* __restrict__ x, const int* __restrict__ rank,
                   float* __restrict__ md) {
    int t = blockIdx.x, d = blockIdx.y, c = threadIdx.x;
    int r = rank[d*LL + t];
    md[(size_t)t*(NDIR*DD0) + d*DD0 + c] = x[((size_t)d*LL + r)*DD0 + c];
}

// ---------------- launch ----------------
extern "C" void kernel_launch(void* const* d_in, const int* in_sizes, int n_in,
                              void* d_out, int out_size, void* d_ws, size_t ws_size,
                              hipStream_t stream) {
    const float* vectors   = (const float*)d_in[0];
    const int*   coords    = (const int*)d_in[1];
    const float* ln_g      = (const float*)d_in[2];
    const float* ln_b      = (const float*)d_in[3];
    const float* Win       = (const float*)d_in[4];
    const float* conv_w    = (const float*)d_in[5];
    const float* conv_b    = (const float*)d_in[6];
    const float* dt_bias   = (const float*)d_in[7];
    const float* A_log     = (const float*)d_in[8];
    const float* Dp        = (const float*)d_in[9];
    const float* rms_g     = (const float*)d_in[10];
    const float* Wout      = (const float*)d_in[11];
    const float* fuse_ln_g = (const float*)d_in[12];
    const float* fuse_ln_b = (const float*)d_in[13];
    const float* fuse_W    = (const float*)d_in[14];
    const float* fuse_b    = (const float*)d_in[15];
    float* out = (float*)d_out;

    char* ws = (char*)d_ws;
    size_t off = 0;
    auto alloc = [&](size_t bytes) -> void* {
        void* p = ws + off;
        off += (bytes + 255) & ~(size_t)255;
        return p;
    };
    int* perm  = (int*)alloc((size_t)NDIR*LL*4);
    int* rank  = (int*)alloc((size_t)NDIR*LL*4);
    float* x   = (float*)alloc((size_t)NDIR*LL*DD0*4);
    float* xn  = (float*)alloc((size_t)NDIR*LL*DD0*4);
    float* zx  = (float*)alloc((size_t)NDIR*LL*DIN*4);
    float* xc  = (float*)alloc((size_t)NDIR*LL*CONV_DIM*4);
    float* dt  = (float*)alloc((size_t)NDIR*LL*HH*4);
    float* dA  = (float*)alloc((size_t)NDIR*LL*HH*4);
    float* ysb = (float*)alloc((size_t)NDIR*LL*DI*4);
    float* u   = (float*)alloc((size_t)NDIR*LL*DI*4);
    float* md  = (float*)alloc((size_t)LL*NDIR*DD0*4);
    float* mdn = (float*)alloc((size_t)LL*NDIR*DD0*4);
    float* cstate = (float*)alloc((size_t)NDIR*NC*HH*PP*NN*4);   // 6 MB
    float* cumdec = (float*)alloc((size_t)NDIR*LL*HH*4);
    (void)ws_size;

    sort_kernel<<<NDIR, 1024, 0, stream>>>(coords, perm, rank);
    gather_kernel<<<dim3(LL, NDIR), 256, 0, stream>>>(vectors, perm, x);

    for (int l = 0; l < NL; ++l) {
        ln_kernel<<<dim3(LL, NDIR), 256, 0, stream>>>(x, xn, ln_g + l*DD0, ln_b + l*DD0,
                                                      DD0, LL, NL*DD0);
        gemm_tile<0><<<dim3((DIN+63)/64, LL/64, NDIR), 256, 0, stream>>>(
            xn, Win + (size_t)l*DD0*DIN, zx, LL, DIN, DD0,
            (size_t)LL*DD0, (size_t)NL*DD0*DIN, (size_t)LL*DIN, nullptr);
        conv_kernel<<<dim3(LL, NDIR), 256, 0, stream>>>(zx, conv_w, conv_b, dt_bias, A_log,
                                                        xc, dt, dA, l);
        scan_pass1<<<NDIR*HH*NC, 256, 0, stream>>>(xc, dt, dA, ysb, cstate, cumdec);
        scan_pass2<<<NDIR*HH, 256, 0, stream>>>(cstate, cumdec);
        scan_pass3<<<NDIR*HH*NC, 256, 0, stream>>>(xc, cumdec, cstate, ysb);
        gate_rms<<<dim3(LL, NDIR), 256, 0, stream>>>(ysb, xc, zx, Dp, rms_g, u, l);
        gemm_tile<1><<<dim3(DD0/64, LL/64, NDIR), 256, 0, stream>>>(
            u, Wout + (size_t)l*DI*DD0, x, LL, DD0, DI,
            (size_t)LL*DI, (size_t)NL*DI*DD0, (size_t)LL*DD0, nullptr);
    }

    concat_kernel<<<dim3(LL, NDIR), 256, 0, stream>>>(x, rank, md);
    ln_kernel<<<dim3(LL, 1), 256, 0, stream>>>(md, mdn, fuse_ln_g, fuse_ln_b,
                                               NDIR*DD0, LL, 0);
    gemm_tile<2><<<dim3(DD0/64, LL/64, 1), 256, 0, stream>>>(
        mdn, fuse_W, out, LL, DD0, NDIR*DD0, 0, 0, 0, fuse_b);
}

// Round 2
// 447.188 us; speedup vs baseline: 3.1070x; 1.5538x over previous
//
#include <hip/hip_runtime.h>
#include <hip/hip_bf16.h>
#include <cstddef>

// Problem constants
#define LL 1024
#define DD0 256
#define NDIR 6
#define NL 2
#define HH 8
#define PP 64
#define NN 32
#define KK 4
#define DI 512           // 2*D
#define DIN 1096         // 2*DI + 2*N + H
#define CONV_DIM 576     // DI + 2*N

// chunked scan config
#define QC 64            // chunk length
#define NC 16            // LL / QC

__constant__ int c_ord[6][3] = {{0,1,2},{0,2,1},{1,0,2},{1,2,0},{2,0,1},{2,1,0}};

typedef __attribute__((ext_vector_type(8))) short bf16x8;
typedef __attribute__((ext_vector_type(4))) float f32x4;

// ---------------- helpers ----------------
__device__ inline float blockReduceSum256(float v) {
    __shared__ float sred[4];
#pragma unroll
    for (int off = 1; off < 64; off <<= 1) v += __shfl_xor(v, off);
    int lane = threadIdx.x & 63, w = threadIdx.x >> 6;
    __syncthreads();               // protect sred from a previous call
    if (lane == 0) sred[w] = v;
    __syncthreads();
    return sred[0] + sred[1] + sred[2] + sred[3];
}

__device__ inline float siluf(float x) { return x / (1.f + expf(-x)); }

// round-to-nearest-even fp32 -> bf16 bits
__device__ inline unsigned short bf16_rn(float x) {
    unsigned u = __float_as_uint(x);
    unsigned r = (u + 0x7fffu + ((u >> 16) & 1u)) >> 16;
    return (unsigned short)r;
}
__device__ inline float bf16_to_f(unsigned short h) {
    return __uint_as_float(((unsigned)h) << 16);
}

// ---------------- sort (lexsort via rank counting) ----------------
__global__ __launch_bounds__(1024)
void sort_kernel(const int* __restrict__ coords, int* __restrict__ perm, int* __restrict__ rank) {
    int d = blockIdx.x;
    int i = threadIdx.x;
    __shared__ unsigned keys[LL];
    int a0 = c_ord[d][0], a1 = c_ord[d][1], a2 = c_ord[d][2];
    unsigned c0 = (unsigned)coords[i*4 + a0];
    unsigned c1 = (unsigned)coords[i*4 + a1];
    unsigned c2 = (unsigned)coords[i*4 + a2];
    unsigned key = (c0 << 22) | (c1 << 16) | (c2 << 10) | (unsigned)i;
    keys[i] = key;
    __syncthreads();
    int r = 0;
    for (int j = 0; j < LL; ++j) r += (keys[j] < key) ? 1 : 0;
    perm[d*LL + r] = i;
    rank[d*LL + i] = r;
}

// ---------------- gather x = vectors[perm] ----------------
__global__ __launch_bounds__(256)
void gather_kernel(const float* __restrict__ vectors, const int* __restrict__ perm,
                   float* __restrict__ x) {
    int t = blockIdx.x, d = blockIdx.y, c = threadIdx.x;
    int src = perm[d*LL + t];
    x[((size_t)d*LL + t)*DD0 + c] = vectors[(size_t)src*DD0 + c];
}

// ---------------- layernorm -> bf16 hi/lo split ----------------
__global__ __launch_bounds__(256)
void ln_split(const float* __restrict__ X, unsigned short* __restrict__ Yh,
              unsigned short* __restrict__ Yl,
              const float* __restrict__ g, const float* __restrict__ b,
              int dd, int rowsPerDir, int gstride) {
    int t = blockIdx.x, d = blockIdx.y;
    const float* xr = X + ((size_t)d*rowsPerDir + t)*dd;
    unsigned short* yh = Yh + ((size_t)d*rowsPerDir + t)*dd;
    unsigned short* yl = Yl + ((size_t)d*rowsPerDir + t)*dd;
    const float* gr = g + (size_t)d*gstride;
    const float* br = b + (size_t)d*gstride;
    float v[6];
    float s = 0.f, s2 = 0.f;
    int cnt = 0;
    for (int c = threadIdx.x; c < dd; c += 256) {
        float xv = xr[c];
        v[cnt++] = xv;
        s += xv; s2 += xv*xv;
    }
    float tot = blockReduceSum256(s);
    float tot2 = blockReduceSum256(s2);
    float mu = tot / dd;
    float var = tot2 / dd - mu*mu;
    float inv = rsqrtf(var + 1e-5f);
    cnt = 0;
    for (int c = threadIdx.x; c < dd; c += 256) {
        float yv = (v[cnt++] - mu) * inv * gr[c] + br[c];
        unsigned short h = bf16_rn(yv);
        yh[c] = h;
        yl[c] = bf16_rn(yv - bf16_to_f(h));
    }
}

// ---------------- tiled transpose + bf16 hi/lo split for weights ----------------
// W: [Kd][Nd] fp32 (batched, stride Kd*Nd) -> Th/Tl: [Nd][Kd] bf16 bits
__global__ __launch_bounds__(256)
void tsplit_kernel(const float* __restrict__ W, unsigned short* __restrict__ Th,
                   unsigned short* __restrict__ Tl, int Kd, int Nd) {
    __shared__ float tile[32][33];
    int j0 = blockIdx.x * 32;   // N
    int i0 = blockIdx.y * 32;   // K
    int c = threadIdx.x & 31, r8 = threadIdx.x >> 5;
    const float* Wz = W + (size_t)blockIdx.z * Kd * Nd;
    unsigned short* Thz = Th + (size_t)blockIdx.z * Nd * Kd;
    unsigned short* Tlz = Tl + (size_t)blockIdx.z * Nd * Kd;
#pragma unroll
    for (int s = 0; s < 4; ++s) {
        int i = i0 + r8 + s*8;
        tile[r8 + s*8][c] = (i < Kd && (j0 + c) < Nd) ? Wz[(size_t)i*Nd + j0 + c] : 0.f;
    }
    __syncthreads();
#pragma unroll
    for (int s = 0; s < 4; ++s) {
        int j = j0 + r8 + s*8;   // output row (n)
        int i = i0 + c;          // output col (k)
        if (j < Nd && i < Kd) {
            float x = tile[c][r8 + s*8];
            unsigned short h = bf16_rn(x);
            Thz[(size_t)j*Kd + i] = h;
            Tlz[(size_t)j*Kd + i] = bf16_rn(x - bf16_to_f(h));
        }
    }
}

// ---------------- split-precision MFMA GEMM ----------------
// C = A@B computed as Ah*Bh + Ah*Bl + Al*Bh  (fp32 accumulate)
// A: [M][K] bf16-bits hi/lo (row-major, k contiguous)
// B: [N][K] bf16-bits hi/lo (TRANSPOSED weights, k contiguous)
// Block tile 128x64, 4 waves (2x2), wave tile 64x32 via 16x16x32 MFMA.
// MODE 0: C = AB ; MODE 1: C += AB ; MODE 2: C = gelu(AB + bias)
template<int MODE>
__global__ __launch_bounds__(256)
void mfma_gemm(const unsigned short* __restrict__ Ahg, const unsigned short* __restrict__ Alg,
               const unsigned short* __restrict__ Bhg, const unsigned short* __restrict__ Blg,
               float* __restrict__ Cg, int N, int K,
               size_t sA, size_t sB, size_t sC, const float* __restrict__ bias) {
    __shared__ unsigned short Ah[128][40];
    __shared__ unsigned short Al[128][40];
    __shared__ unsigned short Bh[64][40];
    __shared__ unsigned short Bl[64][40];
    const unsigned short* Azh = Ahg + (size_t)blockIdx.z * sA;
    const unsigned short* Azl = Alg + (size_t)blockIdx.z * sA;
    const unsigned short* Bzh = Bhg + (size_t)blockIdx.z * sB;
    const unsigned short* Bzl = Blg + (size_t)blockIdx.z * sB;
    float* Cz = Cg + (size_t)blockIdx.z * sC;
    int row0 = blockIdx.y * 128;
    int col0 = blockIdx.x * 64;
    int tid = threadIdx.x;
    int lane = tid & 63, wid = tid >> 6;
    int mbase = (wid >> 1) * 64, nbase = (wid & 1) * 32;
    int lr = lane & 15, lk = (lane >> 4) * 8;

    f32x4 acc[4][2];
#pragma unroll
    for (int m = 0; m < 4; ++m)
#pragma unroll
        for (int n = 0; n < 2; ++n) acc[m][n] = (f32x4){0.f, 0.f, 0.f, 0.f};

    int brow = tid >> 2;            // 0..63 (B staging row = output col)
    int bc8 = (tid & 3) * 8;
    bool bvalid = (col0 + brow) < N;

    for (int k0 = 0; k0 < K; k0 += 32) {
        // stage A (128x32 hi+lo): 2 x 16B per thread each
#pragma unroll
        for (int i = 0; i < 2; ++i) {
            int e = i*256 + tid;
            int r = e >> 2, cc = (e & 3) * 8;
            size_t go = (size_t)(row0 + r)*K + k0 + cc;
            *(uint4*)&Ah[r][cc] = *(const uint4*)(Azh + go);
            *(uint4*)&Al[r][cc] = *(const uint4*)(Azl + go);
        }
        // stage B (64x32 hi+lo): 1 x 16B per thread each
        {
            uint4 vh = {0,0,0,0}, vl = {0,0,0,0};
            if (bvalid) {
                size_t go = (size_t)(col0 + brow)*K + k0 + bc8;
                vh = *(const uint4*)(Bzh + go);
                vl = *(const uint4*)(Bzl + go);
            }
            *(uint4*)&Bh[brow][bc8] = vh;
            *(uint4*)&Bl[brow][bc8] = vl;
        }
        __syncthreads();

        bf16x8 afh[4], afl[4], bfh[2], bfl[2];
#pragma unroll
        for (int mf = 0; mf < 4; ++mf) {
            afh[mf] = *(const bf16x8*)&Ah[mbase + mf*16 + lr][lk];
            afl[mf] = *(const bf16x8*)&Al[mbase + mf*16 + lr][lk];
        }
#pragma unroll
        for (int nf = 0; nf < 2; ++nf) {
            bfh[nf] = *(const bf16x8*)&Bh[nbase + nf*16 + lr][lk];
            bfl[nf] = *(const bf16x8*)&Bl[nbase + nf*16 + lr][lk];
        }
#pragma unroll
        for (int mf = 0; mf < 4; ++mf)
#pragma unroll
            for (int nf = 0; nf < 2; ++nf) {
                acc[mf][nf] = __builtin_amdgcn_mfma_f32_16x16x32_bf16(afh[mf], bfh[nf], acc[mf][nf], 0, 0, 0);
                acc[mf][nf] = __builtin_amdgcn_mfma_f32_16x16x32_bf16(afh[mf], bfl[nf], acc[mf][nf], 0, 0, 0);
                acc[mf][nf] = __builtin_amdgcn_mfma_f32_16x16x32_bf16(afl[mf], bfh[nf], acc[mf][nf], 0, 0, 0);
            }
        __syncthreads();
    }

    // epilogue: C/D layout col = lane&15, row = (lane>>4)*4 + reg
    int crb = (lane >> 4) * 4;
    int cco = lane & 15;
#pragma unroll
    for (int mf = 0; mf < 4; ++mf) {
#pragma unroll
        for (int nf = 0; nf < 2; ++nf) {
            int col = col0 + nbase + nf*16 + cco;
            if (col < N) {
#pragma unroll
                for (int r = 0; r < 4; ++r) {
                    int row = row0 + mbase + mf*16 + crb + r;
                    size_t o = (size_t)row*N + col;
                    float vv = acc[mf][nf][r];
                    if (MODE == 0) Cz[o] = vv;
                    else if (MODE == 1) Cz[o] += vv;
                    else {
                        vv += bias[col];
                        Cz[o] = 0.5f * vv * (1.f + erff(vv * 0.70710678118654752f));
                    }
                }
            }
        }
    }
}

// ---------------- causal depthwise conv (K=4) + silu, and dt/dA ----------------
__global__ __launch_bounds__(256)
void conv_kernel(const float* __restrict__ zx, const float* __restrict__ conv_w,
                 const float* __restrict__ conv_b, const float* __restrict__ dt_bias,
                 const float* __restrict__ A_log, float* __restrict__ xc,
                 float* __restrict__ dt, float* __restrict__ dA, int layer) {
    int t = blockIdx.x, d = blockIdx.y;
    const float* Z = zx + ((size_t)d*LL)*DIN;
    const float* w = conv_w + (size_t)(d*NL + layer)*CONV_DIM*KK;
    const float* b = conv_b + (size_t)(d*NL + layer)*CONV_DIM;
    float* outr = xc + ((size_t)d*LL + t)*CONV_DIM;
    for (int c = threadIdx.x; c < CONV_DIM; c += 256) {
        float acc = b[c];
#pragma unroll
        for (int j = 0; j < KK; ++j) {
            int tt = t - (KK-1) + j;
            if (tt >= 0) acc += Z[(size_t)tt*DIN + DI + c] * w[c*KK + j];
        }
        outr[c] = siluf(acc);
    }
    if (threadIdx.x < HH) {
        int hh = threadIdx.x;
        float v = Z[(size_t)t*DIN + (DIN - HH) + hh] + dt_bias[(d*NL + layer)*HH + hh];
        float sp = (v > 20.f) ? v : log1pf(expf(v));
        dt[((size_t)d*LL + t)*HH + hh] = sp;
        dA[((size_t)d*LL + t)*HH + hh] = expf(-expf(A_log[(d*NL + layer)*HH + hh]) * sp);
    }
}

// ---------------- chunked selective scan (3-pass, exact reassociation) ----------------
__global__ __launch_bounds__(256)
void scan_pass1(const float* __restrict__ xc, const float* __restrict__ dtA,
                const float* __restrict__ dAA, float* __restrict__ ys,
                float* __restrict__ cstate, float* __restrict__ cumdec) {
    int bid = blockIdx.x;
    int c = bid & (NC - 1);
    int hd = bid >> 4;           // log2(NC)=4
    int d = hd >> 3, h = hd & 7;
    int tid = threadIdx.x;
    int p = tid >> 2, g = tid & 3, n0 = g << 3;
    int t0 = c * QC;
    const float* xcd = xc + (size_t)d*LL*CONV_DIM;
    const float* dtd = dtA + (size_t)d*LL*HH + h;
    const float* dAd = dAA + (size_t)d*LL*HH + h;
    float* ysd = ys + (size_t)d*LL*DI + h*PP + p;
    float* cdd = cumdec + (size_t)d*LL*HH + h;

    __shared__ float sdt[QC];
    __shared__ float sdA[QC];
    if (tid < QC) sdt[tid] = dtd[(size_t)(t0 + tid)*HH];
    else if (tid < 2*QC) sdA[tid - QC] = dAd[(size_t)(t0 + tid - QC)*HH];
    __syncthreads();

    float hs[8];
#pragma unroll
    for (int j = 0; j < 8; ++j) hs[j] = 0.f;
    float cum = 1.f;

    const float* row = xcd + (size_t)t0*CONV_DIM;
    float xv = row[h*PP + p];
    float4 b0 = *(const float4*)(row + DI + n0);
    float4 b1 = *(const float4*)(row + DI + n0 + 4);
    float4 c0 = *(const float4*)(row + DI + NN + n0);
    float4 c1 = *(const float4*)(row + DI + NN + n0 + 4);

    for (int tt = 0; tt < QC; ++tt) {
        float nxv = 0.f;
        float4 nb0 = {0,0,0,0}, nb1 = {0,0,0,0}, nc0 = {0,0,0,0}, nc1 = {0,0,0,0};
        if (tt + 1 < QC) {
            const float* r2 = xcd + (size_t)(t0 + tt + 1)*CONV_DIM;
            nxv = r2[h*PP + p];
            nb0 = *(const float4*)(r2 + DI + n0);
            nb1 = *(const float4*)(r2 + DI + n0 + 4);
            nc0 = *(const float4*)(r2 + DI + NN + n0);
            nc1 = *(const float4*)(r2 + DI + NN + n0 + 4);
        }
        float dtv = sdt[tt], dAv = sdA[tt];
        float dtx = dtv * xv;
        float B[8] = {b0.x,b0.y,b0.z,b0.w,b1.x,b1.y,b1.z,b1.w};
        float Cv[8] = {c0.x,c0.y,c0.z,c0.w,c1.x,c1.y,c1.z,c1.w};
        float acc = 0.f;
#pragma unroll
        for (int j = 0; j < 8; ++j) {
            hs[j] = fmaf(dAv, hs[j], dtx * B[j]);
            acc = fmaf(hs[j], Cv[j], acc);
        }
        acc += __shfl_xor(acc, 1);
        acc += __shfl_xor(acc, 2);
        if (g == 0) ysd[(size_t)(t0 + tt)*DI] = acc;
        cum *= dAv;
        if (tid == 0) cdd[(size_t)(t0 + tt)*HH] = cum;
        xv = nxv; b0 = nb0; b1 = nb1; c0 = nc0; c1 = nc1;
    }

    float* cs = cstate + (((size_t)(d*NC + c)*HH + h)*PP + p)*NN + n0;
    float4 s0 = {hs[0], hs[1], hs[2], hs[3]};
    float4 s1 = {hs[4], hs[5], hs[6], hs[7]};
    *(float4*)cs = s0;
    *(float4*)(cs + 4) = s1;
}

__global__ __launch_bounds__(256)
void scan_pass2(float* __restrict__ cstate, const float* __restrict__ cumdec) {
    int hd = blockIdx.x;
    int d = hd >> 3, h = hd & 7;
    int tid = threadIdx.x;
    int p = tid >> 2, g = tid & 3, n0 = g << 3;
    float carry[8];
#pragma unroll
    for (int j = 0; j < 8; ++j) carry[j] = 0.f;
    for (int c = 0; c < NC; ++c) {
        float* cs = cstate + (((size_t)(d*NC + c)*HH + h)*PP + p)*NN + n0;
        float4 s0 = *(const float4*)cs;
        float4 s1 = *(const float4*)(cs + 4);
        float4 w0 = {carry[0], carry[1], carry[2], carry[3]};
        float4 w1 = {carry[4], carry[5], carry[6], carry[7]};
        *(float4*)cs = w0;
        *(float4*)(cs + 4) = w1;
        float dec = cumdec[((size_t)d*LL + (c*QC + QC - 1))*HH + h];
        float s[8] = {s0.x,s0.y,s0.z,s0.w,s1.x,s1.y,s1.z,s1.w};
#pragma unroll
        for (int j = 0; j < 8; ++j) carry[j] = fmaf(dec, carry[j], s[j]);
    }
}

__global__ __launch_bounds__(256)
void scan_pass3(const float* __restrict__ xc, const float* __restrict__ cumdec,
                const float* __restrict__ cstate, float* __restrict__ ys) {
    int bid = blockIdx.x;
    int c = bid & (NC - 1);
    if (c == 0) return;
    int hd = bid >> 4;
    int d = hd >> 3, h = hd & 7;
    int tid = threadIdx.x;
    int p = tid >> 2, g = tid & 3, n0 = g << 3;
    int t0 = c * QC;

    __shared__ float scd[QC];
    if (tid < QC) scd[tid] = cumdec[((size_t)d*LL + t0 + tid)*HH + h];

    const float* cs = cstate + (((size_t)(d*NC + c)*HH + h)*PP + p)*NN + n0;
    float4 h0 = *(const float4*)cs;
    float4 h1 = *(const float4*)(cs + 4);
    float hi[8] = {h0.x,h0.y,h0.z,h0.w,h1.x,h1.y,h1.z,h1.w};
    __syncthreads();

    const float* xcd = xc + (size_t)d*LL*CONV_DIM;
    float* ysd = ys + (size_t)d*LL*DI + h*PP + p;

    for (int tt = 0; tt < QC; ++tt) {
        int t = t0 + tt;
        const float* row = xcd + (size_t)t*CONV_DIM + DI + NN;
        float4 c0 = *(const float4*)(row + n0);
        float4 c1 = *(const float4*)(row + n0 + 4);
        float Cv[8] = {c0.x,c0.y,c0.z,c0.w,c1.x,c1.y,c1.z,c1.w};
        float acc = 0.f;
#pragma unroll
        for (int j = 0; j < 8; ++j) acc = fmaf(hi[j], Cv[j], acc);
        acc += __shfl_xor(acc, 1);
        acc += __shfl_xor(acc, 2);
        if (g == 0) ysd[(size_t)t*DI] += scd[tt] * acc;
    }
}

// ---------------- gating + RMSNorm -> bf16 hi/lo split ----------------
__global__ __launch_bounds__(256)
void gate_rms(const float* __restrict__ ys, const float* __restrict__ xc,
              const float* __restrict__ zx, const float* __restrict__ Dp,
              const float* __restrict__ rms_g, unsigned short* __restrict__ uh,
              unsigned short* __restrict__ ul, int layer) {
    int t = blockIdx.x, d = blockIdx.y;
    const float* ysr = ys + ((size_t)d*LL + t)*DI;
    const float* xcr = xc + ((size_t)d*LL + t)*CONV_DIM;
    const float* zr = zx + ((size_t)d*LL + t)*DIN;
    const float* Dpd = Dp + (d*NL + layer)*HH;
    const float* rg = rms_g + (size_t)(d*NL + layer)*DI;
    unsigned short* uhr = uh + ((size_t)d*LL + t)*DI;
    unsigned short* ulr = ul + ((size_t)d*LL + t)*DI;
    float vals[2];
    float ss = 0.f;
#pragma unroll
    for (int i = 0; i < 2; ++i) {
        int c = threadIdx.x + i*256;
        float xsv = xcr[c];
        int hh = c >> 6;
        float yv = ysr[c] + Dpd[hh] * xsv;
        float zv = zr[c];
        float uv = yv * siluf(zv);
        vals[i] = uv;
        ss += uv * uv;
    }
    float tot = blockReduceSum256(ss);
    float scale = rsqrtf(tot / DI + 1e-5f);
#pragma unroll
    for (int i = 0; i < 2; ++i) {
        int c = threadIdx.x + i*256;
        float uv = vals[i] * scale * rg[c];
        unsigned short h = bf16_rn(uv);
        uhr[c] = h;
        ulr[c] = bf16_rn(uv - bf16_to_f(h));
    }
}

// ---------------- concat (inverse permute + pack) ----------------
__global__ __launch_bounds__(256)
void concat_kernel(const float* __restrict__ x, const int* __restrict__ rank,
                   float* __restrict__ md) {
    int t = blockIdx.x, d = blockIdx.y, c = threadIdx.x;
    int r = rank[d*LL + t];
    md[(size_t)t*(NDIR*DD0) + d*DD0 + c] = x[((size_t)d*LL + r)*DD0 + c];
}

// ---------------- launch ----------------
extern "C" void kernel_launch(void* const* d_in, const int* in_sizes, int n_in,
                              void* d_out, int out_size, void* d_ws, size_t ws_size,
                              hipStream_t stream) {
    const float* vectors   = (const float*)d_in[0];
    const int*   coords    = (const int*)d_in[1];
    const float* ln_g      = (const float*)d_in[2];
    const float* ln_b      = (const float*)d_in[3];
    const float* Win       = (const float*)d_in[4];
    const float* conv_w    = (const float*)d_in[5];
    const float* conv_b    = (const float*)d_in[6];
    const float* dt_bias   = (const float*)d_in[7];
    const float* A_log     = (const float*)d_in[8];
    const float* Dp        = (const float*)d_in[9];
    const float* rms_g     = (const float*)d_in[10];
    const float* Wout      = (const float*)d_in[11];
    const float* fuse_ln_g = (const float*)d_in[12];
    const float* fuse_ln_b = (const float*)d_in[13];
    const float* fuse_W    = (const float*)d_in[14];
    const float* fuse_b    = (const float*)d_in[15];
    float* out = (float*)d_out;

    char* ws = (char*)d_ws;
    size_t off = 0;
    auto alloc = [&](size_t bytes) -> void* {
        void* p = ws + off;
        off += (bytes + 255) & ~(size_t)255;
        return p;
    };
    int* perm  = (int*)alloc((size_t)NDIR*LL*4);
    int* rank  = (int*)alloc((size_t)NDIR*LL*4);
    float* x   = (float*)alloc((size_t)NDIR*LL*DD0*4);
    unsigned short* xnh = (unsigned short*)alloc((size_t)NDIR*LL*DD0*2);
    unsigned short* xnl = (unsigned short*)alloc((size_t)NDIR*LL*DD0*2);
    float* zx  = (float*)alloc((size_t)NDIR*LL*DIN*4);
    float* xc  = (float*)alloc((size_t)NDIR*LL*CONV_DIM*4);
    float* dt  = (float*)alloc((size_t)NDIR*LL*HH*4);
    float* dA  = (float*)alloc((size_t)NDIR*LL*HH*4);
    float* ysb = (float*)alloc((size_t)NDIR*LL*DI*4);
    unsigned short* uh = (unsigned short*)alloc((size_t)NDIR*LL*DI*2);
    unsigned short* ul = (unsigned short*)alloc((size_t)NDIR*LL*DI*2);
    float* cstate = (float*)alloc((size_t)NDIR*NC*HH*PP*NN*4);
    float* cumdec = (float*)alloc((size_t)NDIR*LL*HH*4);
    unsigned short* WinTh  = (unsigned short*)alloc((size_t)NDIR*NL*DIN*DD0*2);
    unsigned short* WinTl  = (unsigned short*)alloc((size_t)NDIR*NL*DIN*DD0*2);
    unsigned short* WoutTh = (unsigned short*)alloc((size_t)NDIR*NL*DD0*DI*2);
    unsigned short* WoutTl = (unsigned short*)alloc((size_t)NDIR*NL*DD0*DI*2);
    unsigned short* fWTh   = (unsigned short*)alloc((size_t)DD0*(NDIR*DD0)*2);
    unsigned short* fWTl   = (unsigned short*)alloc((size_t)DD0*(NDIR*DD0)*2);
    // alias md/mdn onto the (dead by then) uh/ul region
    float* md = (float*)uh;                                   // 6*1024*512*2 = 1024*1536*4 bytes
    unsigned short* mdnh = (unsigned short*)ul;               // 1024*1536*2
    unsigned short* mdnl = mdnh + (size_t)LL*(NDIR*DD0);      // 1024*1536*2
    (void)ws_size;

    sort_kernel<<<NDIR, 1024, 0, stream>>>(coords, perm, rank);
    gather_kernel<<<dim3(LL, NDIR), 256, 0, stream>>>(vectors, perm, x);

    // weight transpose + split (once per launch)
    tsplit_kernel<<<dim3((DIN+31)/32, DD0/32, NDIR*NL), 256, 0, stream>>>(Win, WinTh, WinTl, DD0, DIN);
    tsplit_kernel<<<dim3(DD0/32, DI/32, NDIR*NL), 256, 0, stream>>>(Wout, WoutTh, WoutTl, DI, DD0);
    tsplit_kernel<<<dim3(DD0/32, (NDIR*DD0)/32, 1), 256, 0, stream>>>(fuse_W, fWTh, fWTl, NDIR*DD0, DD0);

    for (int l = 0; l < NL; ++l) {
        ln_split<<<dim3(LL, NDIR), 256, 0, stream>>>(x, xnh, xnl, ln_g + l*DD0, ln_b + l*DD0,
                                                     DD0, LL, NL*DD0);
        mfma_gemm<0><<<dim3((DIN+63)/64, LL/128, NDIR), 256, 0, stream>>>(
            xnh, xnl, WinTh + (size_t)l*DIN*DD0, WinTl + (size_t)l*DIN*DD0, zx,
            DIN, DD0, (size_t)LL*DD0, (size_t)NL*DIN*DD0, (size_t)LL*DIN, nullptr);
        conv_kernel<<<dim3(LL, NDIR), 256, 0, stream>>>(zx, conv_w, conv_b, dt_bias, A_log,
                                                        xc, dt, dA, l);
        scan_pass1<<<NDIR*HH*NC, 256, 0, stream>>>(xc, dt, dA, ysb, cstate, cumdec);
        scan_pass2<<<NDIR*HH, 256, 0, stream>>>(cstate, cumdec);
        scan_pass3<<<NDIR*HH*NC, 256, 0, stream>>>(xc, cumdec, cstate, ysb);
        gate_rms<<<dim3(LL, NDIR), 256, 0, stream>>>(ysb, xc, zx, Dp, rms_g, uh, ul, l);
        mfma_gemm<1><<<dim3(DD0/64, LL/128, NDIR), 256, 0, stream>>>(
            uh, ul, WoutTh + (size_t)l*DD0*DI, WoutTl + (size_t)l*DD0*DI, x,
            DD0, DI, (size_t)LL*DI, (size_t)NL*DD0*DI, (size_t)LL*DD0, nullptr);
    }

    concat_kernel<<<dim3(LL, NDIR), 256, 0, stream>>>(x, rank, md);
    ln_split<<<dim3(LL, 1), 256, 0, stream>>>(md, mdnh, mdnl, fuse_ln_g, fuse_ln_b,
                                              NDIR*DD0, LL, 0);
    mfma_gemm<2><<<dim3(DD0/64, LL/128, 1), 256, 0, stream>>>(
        mdnh, mdnl, fWTh, fWTl, out, DD0, NDIR*DD0, 0, 0, 0, fuse_b);
}

// Round 3
// 428.872 us; speedup vs baseline: 3.2397x; 1.0427x over previous
//
#include <hip/hip_runtime.h>
#include <hip/hip_bf16.h>
#include <cstddef>

// Problem constants
#define LL 1024
#define DD0 256
#define NDIR 6
#define NL 2
#define HH 8
#define PP 64
#define NN 32
#define KK 4
#define DI 512           // 2*D
#define DIN 1096         // 2*DI + 2*N + H
#define CONV_DIM 576     // DI + 2*N

// chunked scan config
#define QC 64            // chunk length
#define NC 16            // LL / QC

__constant__ int c_ord[6][3] = {{0,1,2},{0,2,1},{1,0,2},{1,2,0},{2,0,1},{2,1,0}};

typedef __attribute__((ext_vector_type(8))) short bf16x8;
typedef __attribute__((ext_vector_type(4))) float f32x4;

// ---------------- helpers ----------------
__device__ inline float blockReduceSum256(float v) {
    __shared__ float sred[4];
#pragma unroll
    for (int off = 1; off < 64; off <<= 1) v += __shfl_xor(v, off);
    int lane = threadIdx.x & 63, w = threadIdx.x >> 6;
    __syncthreads();               // protect sred from a previous call
    if (lane == 0) sred[w] = v;
    __syncthreads();
    return sred[0] + sred[1] + sred[2] + sred[3];
}

__device__ inline float siluf(float x) { return x / (1.f + expf(-x)); }

// round-to-nearest-even fp32 -> bf16 bits
__device__ inline unsigned short bf16_rn(float x) {
    unsigned u = __float_as_uint(x);
    unsigned r = (u + 0x7fffu + ((u >> 16) & 1u)) >> 16;
    return (unsigned short)r;
}
__device__ inline float bf16_to_f(unsigned short h) {
    return __uint_as_float(((unsigned)h) << 16);
}

// ---------------- sort (lexsort via rank counting) ----------------
__global__ __launch_bounds__(1024)
void sort_kernel(const int* __restrict__ coords, int* __restrict__ perm, int* __restrict__ rank) {
    int d = blockIdx.x;
    int i = threadIdx.x;
    __shared__ unsigned keys[LL];
    int a0 = c_ord[d][0], a1 = c_ord[d][1], a2 = c_ord[d][2];
    unsigned c0 = (unsigned)coords[i*4 + a0];
    unsigned c1 = (unsigned)coords[i*4 + a1];
    unsigned c2 = (unsigned)coords[i*4 + a2];
    unsigned key = (c0 << 22) | (c1 << 16) | (c2 << 10) | (unsigned)i;
    keys[i] = key;
    __syncthreads();
    int r = 0;
    for (int j = 0; j < LL; ++j) r += (keys[j] < key) ? 1 : 0;
    perm[d*LL + r] = i;
    rank[d*LL + i] = r;
}

// ---------------- gather x = vectors[perm] ----------------
__global__ __launch_bounds__(256)
void gather_kernel(const float* __restrict__ vectors, const int* __restrict__ perm,
                   float* __restrict__ x) {
    int t = blockIdx.x, d = blockIdx.y, c = threadIdx.x;
    int src = perm[d*LL + t];
    x[((size_t)d*LL + t)*DD0 + c] = vectors[(size_t)src*DD0 + c];
}

// ---------------- layernorm -> bf16 hi/lo split ----------------
__global__ __launch_bounds__(256)
void ln_split(const float* __restrict__ X, unsigned short* __restrict__ Yh,
              unsigned short* __restrict__ Yl,
              const float* __restrict__ g, const float* __restrict__ b,
              int dd, int rowsPerDir, int gstride) {
    int t = blockIdx.x, d = blockIdx.y;
    const float* xr = X + ((size_t)d*rowsPerDir + t)*dd;
    unsigned short* yh = Yh + ((size_t)d*rowsPerDir + t)*dd;
    unsigned short* yl = Yl + ((size_t)d*rowsPerDir + t)*dd;
    const float* gr = g + (size_t)d*gstride;
    const float* br = b + (size_t)d*gstride;
    float v[6];
    float s = 0.f, s2 = 0.f;
    int cnt = 0;
    for (int c = threadIdx.x; c < dd; c += 256) {
        float xv = xr[c];
        v[cnt++] = xv;
        s += xv; s2 += xv*xv;
    }
    float tot = blockReduceSum256(s);
    float tot2 = blockReduceSum256(s2);
    float mu = tot / dd;
    float var = tot2 / dd - mu*mu;
    float inv = rsqrtf(var + 1e-5f);
    cnt = 0;
    for (int c = threadIdx.x; c < dd; c += 256) {
        float yv = (v[cnt++] - mu) * inv * gr[c] + br[c];
        unsigned short h = bf16_rn(yv);
        yh[c] = h;
        yl[c] = bf16_rn(yv - bf16_to_f(h));
    }
}

// ---------------- tiled transpose + bf16 hi/lo split for weights ----------------
// W: [Kd][Nd] fp32 (batched, stride Kd*Nd) -> Th/Tl: [Nd][Kd] bf16 bits
__global__ __launch_bounds__(256)
void tsplit_kernel(const float* __restrict__ W, unsigned short* __restrict__ Th,
                   unsigned short* __restrict__ Tl, int Kd, int Nd) {
    __shared__ float tile[32][33];
    int j0 = blockIdx.x * 32;   // N
    int i0 = blockIdx.y * 32;   // K
    int c = threadIdx.x & 31, r8 = threadIdx.x >> 5;
    const float* Wz = W + (size_t)blockIdx.z * Kd * Nd;
    unsigned short* Thz = Th + (size_t)blockIdx.z * Nd * Kd;
    unsigned short* Tlz = Tl + (size_t)blockIdx.z * Nd * Kd;
#pragma unroll
    for (int s = 0; s < 4; ++s) {
        int i = i0 + r8 + s*8;
        tile[r8 + s*8][c] = (i < Kd && (j0 + c) < Nd) ? Wz[(size_t)i*Nd + j0 + c] : 0.f;
    }
    __syncthreads();
#pragma unroll
    for (int s = 0; s < 4; ++s) {
        int j = j0 + r8 + s*8;   // output row (n)
        int i = i0 + c;          // output col (k)
        if (j < Nd && i < Kd) {
            float x = tile[c][r8 + s*8];
            unsigned short h = bf16_rn(x);
            Thz[(size_t)j*Kd + i] = h;
            Tlz[(size_t)j*Kd + i] = bf16_rn(x - bf16_to_f(h));
        }
    }
}

// ---------------- split-precision MFMA GEMM, 2-deep prefetch pipeline ----------------
// C = A@B computed as Ah*Bh + Ah*Bl + Al*Bh  (fp32 accumulate)
// A: [M][K] bf16-bits hi/lo (row-major, k contiguous)
// B: [N][K] bf16-bits hi/lo (TRANSPOSED weights, k contiguous)
// Block tile 128x64, 4 waves (2x2), wave tile 64x32 via 16x16x32 MFMA.
// Pipeline: register-staged prefetch 2 K-tiles ahead, double-buffered LDS,
// ONE barrier per K-step; compiler's auto-waitcnt gives counted vmcnt.
// MODE 0: C = AB ; MODE 1: C += AB ; MODE 2: C = gelu(AB + bias)
template<int MODE>
__global__ __launch_bounds__(256)
void mfma_gemm(const unsigned short* __restrict__ Ahg, const unsigned short* __restrict__ Alg,
               const unsigned short* __restrict__ Bhg, const unsigned short* __restrict__ Blg,
               float* __restrict__ Cg, int N, int K,
               size_t sA, size_t sB, size_t sC, const float* __restrict__ bias) {
    __shared__ unsigned short AhS[2][128][40];
    __shared__ unsigned short AlS[2][128][40];
    __shared__ unsigned short BhS[2][64][40];
    __shared__ unsigned short BlS[2][64][40];
    const unsigned short* Azh = Ahg + (size_t)blockIdx.z * sA;
    const unsigned short* Azl = Alg + (size_t)blockIdx.z * sA;
    const unsigned short* Bzh = Bhg + (size_t)blockIdx.z * sB;
    const unsigned short* Bzl = Blg + (size_t)blockIdx.z * sB;
    float* Cz = Cg + (size_t)blockIdx.z * sC;
    int row0 = blockIdx.y * 128;
    int col0 = blockIdx.x * 64;
    int tid = threadIdx.x;
    int lane = tid & 63, wid = tid >> 6;
    int mbase = (wid >> 1) * 64, nbase = (wid & 1) * 32;
    int lr = lane & 15, lk = (lane >> 4) * 8;

    // staging thread mapping
    int ar0 = tid >> 2;          // A rows tid>>2 and 64+(tid>>2)
    int ar1 = 64 + (tid >> 2);
    int ac  = (tid & 3) * 8;
    int brow = tid >> 2;         // B staging row = output col
    int bc8 = (tid & 3) * 8;
    bool bvalid = (col0 + brow) < N;
    const uint4 z4 = {0u,0u,0u,0u};

    f32x4 acc[4][2];
#pragma unroll
    for (int m = 0; m < 4; ++m)
#pragma unroll
        for (int n = 0; n < 2; ++n) acc[m][n] = (f32x4){0.f, 0.f, 0.f, 0.f};

    // two named register sets (rule: no runtime-indexed reg arrays)
    uint4 s0a0, s0a1, s0l0, s0l1, s0bh, s0bl;
    uint4 s1a0, s1a1, s1l0, s1l1, s1bh, s1bl;

#define LOAD_TILE(Ra0,Ra1,Rl0,Rl1,Rbh,Rbl,kt) do {                          \
        size_t ka = (size_t)(kt) * 32;                                       \
        size_t g0 = (size_t)(row0 + ar0)*K + ka + ac;                        \
        size_t g1 = (size_t)(row0 + ar1)*K + ka + ac;                        \
        Ra0 = *(const uint4*)(Azh + g0);                                     \
        Ra1 = *(const uint4*)(Azh + g1);                                     \
        Rl0 = *(const uint4*)(Azl + g0);                                     \
        Rl1 = *(const uint4*)(Azl + g1);                                     \
        if (bvalid) {                                                        \
            size_t gb = (size_t)(col0 + brow)*K + ka + bc8;                  \
            Rbh = *(const uint4*)(Bzh + gb);                                 \
            Rbl = *(const uint4*)(Bzl + gb);                                 \
        } else { Rbh = z4; Rbl = z4; }                                       \
    } while (0)

#define WRITE_TILE(buf,Ra0,Ra1,Rl0,Rl1,Rbh,Rbl) do {                         \
        *(uint4*)&AhS[buf][ar0][ac] = Ra0;                                   \
        *(uint4*)&AhS[buf][ar1][ac] = Ra1;                                   \
        *(uint4*)&AlS[buf][ar0][ac] = Rl0;                                   \
        *(uint4*)&AlS[buf][ar1][ac] = Rl1;                                   \
        *(uint4*)&BhS[buf][brow][bc8] = Rbh;                                 \
        *(uint4*)&BlS[buf][brow][bc8] = Rbl;                                 \
    } while (0)

#define COMPUTE(buf) do {                                                    \
        bf16x8 afh[4], afl[4], bfh[2], bfl[2];                               \
        _Pragma("unroll")                                                    \
        for (int mf = 0; mf < 4; ++mf) {                                     \
            afh[mf] = *(const bf16x8*)&AhS[buf][mbase + mf*16 + lr][lk];     \
            afl[mf] = *(const bf16x8*)&AlS[buf][mbase + mf*16 + lr][lk];     \
        }                                                                    \
        _Pragma("unroll")                                                    \
        for (int nf = 0; nf < 2; ++nf) {                                     \
            bfh[nf] = *(const bf16x8*)&BhS[buf][nbase + nf*16 + lr][lk];     \
            bfl[nf] = *(const bf16x8*)&BlS[buf][nbase + nf*16 + lr][lk];     \
        }                                                                    \
        _Pragma("unroll")                                                    \
        for (int mf = 0; mf < 4; ++mf)                                       \
            _Pragma("unroll")                                                \
            for (int nf = 0; nf < 2; ++nf) {                                 \
                acc[mf][nf] = __builtin_amdgcn_mfma_f32_16x16x32_bf16(afh[mf], bfh[nf], acc[mf][nf], 0, 0, 0); \
                acc[mf][nf] = __builtin_amdgcn_mfma_f32_16x16x32_bf16(afh[mf], bfl[nf], acc[mf][nf], 0, 0, 0); \
                acc[mf][nf] = __builtin_amdgcn_mfma_f32_16x16x32_bf16(afl[mf], bfh[nf], acc[mf][nf], 0, 0, 0); \
            }                                                                \
    } while (0)

    int nt = K >> 5;   // # of 32-wide K-tiles; always even here (8,16,48)

    // prologue: tiles 0 and 1 in flight; write tile 0 to LDS buf0
    LOAD_TILE(s0a0, s0a1, s0l0, s0l1, s0bh, s0bl, 0);
    LOAD_TILE(s1a0, s1a1, s1l0, s1l1, s1bh, s1bl, 1);
    WRITE_TILE(0, s0a0, s0a1, s0l0, s0l1, s0bh, s0bl);   // auto vmcnt waits set0 only
    __syncthreads();

    for (int t = 0; t < nt; t += 2) {
        // even step: compute tile t from buf0; set1 holds tile t+1
        if (t + 2 < nt) LOAD_TILE(s0a0, s0a1, s0l0, s0l1, s0bh, s0bl, t + 2);
        COMPUTE(0);
        WRITE_TILE(1, s1a0, s1a1, s1l0, s1l1, s1bh, s1bl);
        __syncthreads();
        // odd step: compute tile t+1 from buf1; set0 holds tile t+2
        if (t + 3 < nt) LOAD_TILE(s1a0, s1a1, s1l0, s1l1, s1bh, s1bl, t + 3);
        COMPUTE(1);
        if (t + 2 < nt) WRITE_TILE(0, s0a0, s0a1, s0l0, s0l1, s0bh, s0bl);
        __syncthreads();
    }

#undef LOAD_TILE
#undef WRITE_TILE
#undef COMPUTE

    // epilogue: C/D layout col = lane&15, row = (lane>>4)*4 + reg
    int crb = (lane >> 4) * 4;
    int cco = lane & 15;
#pragma unroll
    for (int mf = 0; mf < 4; ++mf) {
#pragma unroll
        for (int nf = 0; nf < 2; ++nf) {
            int col = col0 + nbase + nf*16 + cco;
            if (col < N) {
#pragma unroll
                for (int r = 0; r < 4; ++r) {
                    int row = row0 + mbase + mf*16 + crb + r;
                    size_t o = (size_t)row*N + col;
                    float vv = acc[mf][nf][r];
                    if (MODE == 0) Cz[o] = vv;
                    else if (MODE == 1) Cz[o] += vv;
                    else {
                        vv += bias[col];
                        Cz[o] = 0.5f * vv * (1.f + erff(vv * 0.70710678118654752f));
                    }
                }
            }
        }
    }
}

// ---------------- causal depthwise conv (K=4) + silu, and dt/dA ----------------
__global__ __launch_bounds__(256)
void conv_kernel(const float* __restrict__ zx, const float* __restrict__ conv_w,
                 const float* __restrict__ conv_b, const float* __restrict__ dt_bias,
                 const float* __restrict__ A_log, float* __restrict__ xc,
                 float* __restrict__ dt, float* __restrict__ dA, int layer) {
    int t = blockIdx.x, d = blockIdx.y;
    const float* Z = zx + ((size_t)d*LL)*DIN;
    const float* w = conv_w + (size_t)(d*NL + layer)*CONV_DIM*KK;
    const float* b = conv_b + (size_t)(d*NL + layer)*CONV_DIM;
    float* outr = xc + ((size_t)d*LL + t)*CONV_DIM;
    for (int c = threadIdx.x; c < CONV_DIM; c += 256) {
        float acc = b[c];
#pragma unroll
        for (int j = 0; j < KK; ++j) {
            int tt = t - (KK-1) + j;
            if (tt >= 0) acc += Z[(size_t)tt*DIN + DI + c] * w[c*KK + j];
        }
        outr[c] = siluf(acc);
    }
    if (threadIdx.x < HH) {
        int hh = threadIdx.x;
        float v = Z[(size_t)t*DIN + (DIN - HH) + hh] + dt_bias[(d*NL + layer)*HH + hh];
        float sp = (v > 20.f) ? v : log1pf(expf(v));
        dt[((size_t)d*LL + t)*HH + hh] = sp;
        dA[((size_t)d*LL + t)*HH + hh] = expf(-expf(A_log[(d*NL + layer)*HH + hh]) * sp);
    }
}

// ---------------- chunked selective scan (3-pass, exact reassociation) ----------------
__global__ __launch_bounds__(256)
void scan_pass1(const float* __restrict__ xc, const float* __restrict__ dtA,
                const float* __restrict__ dAA, float* __restrict__ ys,
                float* __restrict__ cstate, float* __restrict__ cumdec) {
    int bid = blockIdx.x;
    int c = bid & (NC - 1);
    int hd = bid >> 4;           // log2(NC)=4
    int d = hd >> 3, h = hd & 7;
    int tid = threadIdx.x;
    int p = tid >> 2, g = tid & 3, n0 = g << 3;
    int t0 = c * QC;
    const float* xcd = xc + (size_t)d*LL*CONV_DIM;
    const float* dtd = dtA + (size_t)d*LL*HH + h;
    const float* dAd = dAA + (size_t)d*LL*HH + h;
    float* ysd = ys + (size_t)d*LL*DI + h*PP + p;
    float* cdd = cumdec + (size_t)d*LL*HH + h;

    __shared__ float sdt[QC];
    __shared__ float sdA[QC];
    if (tid < QC) sdt[tid] = dtd[(size_t)(t0 + tid)*HH];
    else if (tid < 2*QC) sdA[tid - QC] = dAd[(size_t)(t0 + tid - QC)*HH];
    __syncthreads();

    float hs[8];
#pragma unroll
    for (int j = 0; j < 8; ++j) hs[j] = 0.f;
    float cum = 1.f;

    const float* row = xcd + (size_t)t0*CONV_DIM;
    float xv = row[h*PP + p];
    float4 b0 = *(const float4*)(row + DI + n0);
    float4 b1 = *(const float4*)(row + DI + n0 + 4);
    float4 c0 = *(const float4*)(row + DI + NN + n0);
    float4 c1 = *(const float4*)(row + DI + NN + n0 + 4);

    for (int tt = 0; tt < QC; ++tt) {
        float nxv = 0.f;
        float4 nb0 = {0,0,0,0}, nb1 = {0,0,0,0}, nc0 = {0,0,0,0}, nc1 = {0,0,0,0};
        if (tt + 1 < QC) {
            const float* r2 = xcd + (size_t)(t0 + tt + 1)*CONV_DIM;
            nxv = r2[h*PP + p];
            nb0 = *(const float4*)(r2 + DI + n0);
            nb1 = *(const float4*)(r2 + DI + n0 + 4);
            nc0 = *(const float4*)(r2 + DI + NN + n0);
            nc1 = *(const float4*)(r2 + DI + NN + n0 + 4);
        }
        float dtv = sdt[tt], dAv = sdA[tt];
        float dtx = dtv * xv;
        float B[8] = {b0.x,b0.y,b0.z,b0.w,b1.x,b1.y,b1.z,b1.w};
        float Cv[8] = {c0.x,c0.y,c0.z,c0.w,c1.x,c1.y,c1.z,c1.w};
        float acc = 0.f;
#pragma unroll
        for (int j = 0; j < 8; ++j) {
            hs[j] = fmaf(dAv, hs[j], dtx * B[j]);
            acc = fmaf(hs[j], Cv[j], acc);
        }
        acc += __shfl_xor(acc, 1);
        acc += __shfl_xor(acc, 2);
        if (g == 0) ysd[(size_t)(t0 + tt)*DI] = acc;
        cum *= dAv;
        if (tid == 0) cdd[(size_t)(t0 + tt)*HH] = cum;
        xv = nxv; b0 = nb0; b1 = nb1; c0 = nc0; c1 = nc1;
    }

    float* cs = cstate + (((size_t)(d*NC + c)*HH + h)*PP + p)*NN + n0;
    float4 s0 = {hs[0], hs[1], hs[2], hs[3]};
    float4 s1 = {hs[4], hs[5], hs[6], hs[7]};
    *(float4*)cs = s0;
    *(float4*)(cs + 4) = s1;
}

__global__ __launch_bounds__(256)
void scan_pass2(float* __restrict__ cstate, const float* __restrict__ cumdec) {
    int hd = blockIdx.x;
    int d = hd >> 3, h = hd & 7;
    int tid = threadIdx.x;
    int p = tid >> 2, g = tid & 3, n0 = g << 3;
    float carry[8];
#pragma unroll
    for (int j = 0; j < 8; ++j) carry[j] = 0.f;
    for (int c = 0; c < NC; ++c) {
        float* cs = cstate + (((size_t)(d*NC + c)*HH + h)*PP + p)*NN + n0;
        float4 s0 = *(const float4*)cs;
        float4 s1 = *(const float4*)(cs + 4);
        float4 w0 = {carry[0], carry[1], carry[2], carry[3]};
        float4 w1 = {carry[4], carry[5], carry[6], carry[7]};
        *(float4*)cs = w0;
        *(float4*)(cs + 4) = w1;
        float dec = cumdec[((size_t)d*LL + (c*QC + QC - 1))*HH + h];
        float s[8] = {s0.x,s0.y,s0.z,s0.w,s1.x,s1.y,s1.z,s1.w};
#pragma unroll
        for (int j = 0; j < 8; ++j) carry[j] = fmaf(dec, carry[j], s[j]);
    }
}

__global__ __launch_bounds__(256)
void scan_pass3(const float* __restrict__ xc, const float* __restrict__ cumdec,
                const float* __restrict__ cstate, float* __restrict__ ys) {
    int bid = blockIdx.x;
    int c = bid & (NC - 1);
    if (c == 0) return;
    int hd = bid >> 4;
    int d = hd >> 3, h = hd & 7;
    int tid = threadIdx.x;
    int p = tid >> 2, g = tid & 3, n0 = g << 3;
    int t0 = c * QC;

    __shared__ float scd[QC];
    if (tid < QC) scd[tid] = cumdec[((size_t)d*LL + t0 + tid)*HH + h];

    const float* cs = cstate + (((size_t)(d*NC + c)*HH + h)*PP + p)*NN + n0;
    float4 h0 = *(const float4*)cs;
    float4 h1 = *(const float4*)(cs + 4);
    float hi[8] = {h0.x,h0.y,h0.z,h0.w,h1.x,h1.y,h1.z,h1.w};
    __syncthreads();

    const float* xcd = xc + (size_t)d*LL*CONV_DIM;
    float* ysd = ys + (size_t)d*LL*DI + h*PP + p;

    for (int tt = 0; tt < QC; ++tt) {
        int t = t0 + tt;
        const float* row = xcd + (size_t)t*CONV_DIM + DI + NN;
        float4 c0 = *(const float4*)(row + n0);
        float4 c1 = *(const float4*)(row + n0 + 4);
        float Cv[8] = {c0.x,c0.y,c0.z,c0.w,c1.x,c1.y,c1.z,c1.w};
        float acc = 0.f;
#pragma unroll
        for (int j = 0; j < 8; ++j) acc = fmaf(hi[j], Cv[j], acc);
        acc += __shfl_xor(acc, 1);
        acc += __shfl_xor(acc, 2);
        if (g == 0) ysd[(size_t)t*DI] += scd[tt] * acc;
    }
}

// ---------------- gating + RMSNorm -> bf16 hi/lo split ----------------
__global__ __launch_bounds__(256)
void gate_rms(const float* __restrict__ ys, const float* __restrict__ xc,
              const float* __restrict__ zx, const float* __restrict__ Dp,
              const float* __restrict__ rms_g, unsigned short* __restrict__ uh,
              unsigned short* __restrict__ ul, int layer) {
    int t = blockIdx.x, d = blockIdx.y;
    const float* ysr = ys + ((size_t)d*LL + t)*DI;
    const float* xcr = xc + ((size_t)d*LL + t)*CONV_DIM;
    const float* zr = zx + ((size_t)d*LL + t)*DIN;
    const float* Dpd = Dp + (d*NL + layer)*HH;
    const float* rg = rms_g + (size_t)(d*NL + layer)*DI;
    unsigned short* uhr = uh + ((size_t)d*LL + t)*DI;
    unsigned short* ulr = ul + ((size_t)d*LL + t)*DI;
    float vals[2];
    float ss = 0.f;
#pragma unroll
    for (int i = 0; i < 2; ++i) {
        int c = threadIdx.x + i*256;
        float xsv = xcr[c];
        int hh = c >> 6;
        float yv = ysr[c] + Dpd[hh] * xsv;
        float zv = zr[c];
        float uv = yv * siluf(zv);
        vals[i] = uv;
        ss += uv * uv;
    }
    float tot = blockReduceSum256(ss);
    float scale = rsqrtf(tot / DI + 1e-5f);
#pragma unroll
    for (int i = 0; i < 2; ++i) {
        int c = threadIdx.x + i*256;
        float uv = vals[i] * scale * rg[c];
        unsigned short h = bf16_rn(uv);
        uhr[c] = h;
        ulr[c] = bf16_rn(uv - bf16_to_f(h));
    }
}

// ---------------- concat (inverse permute + pack) ----------------
__global__ __launch_bounds__(256)
void concat_kernel(const float* __restrict__ x, const int* __restrict__ rank,
                   float* __restrict__ md) {
    int t = blockIdx.x, d = blockIdx.y, c = threadIdx.x;
    int r = rank[d*LL + t];
    md[(size_t)t*(NDIR*DD0) + d*DD0 + c] = x[((size_t)d*LL + r)*DD0 + c];
}

// ---------------- launch ----------------
extern "C" void kernel_launch(void* const* d_in, const int* in_sizes, int n_in,
                              void* d_out, int out_size, void* d_ws, size_t ws_size,
                              hipStream_t stream) {
    const float* vectors   = (const float*)d_in[0];
    const int*   coords    = (const int*)d_in[1];
    const float* ln_g      = (const float*)d_in[2];
    const float* ln_b      = (const float*)d_in[3];
    const float* Win       = (const float*)d_in[4];
    const float* conv_w    = (const float*)d_in[5];
    const float* conv_b    = (const float*)d_in[6];
    const float* dt_bias   = (const float*)d_in[7];
    const float* A_log     = (const float*)d_in[8];
    const float* Dp        = (const float*)d_in[9];
    const float* rms_g     = (const float*)d_in[10];
    const float* Wout      = (const float*)d_in[11];
    const float* fuse_ln_g = (const float*)d_in[12];
    const float* fuse_ln_b = (const float*)d_in[13];
    const float* fuse_W    = (const float*)d_in[14];
    const float* fuse_b    = (const float*)d_in[15];
    float* out = (float*)d_out;

    char* ws = (char*)d_ws;
    size_t off = 0;
    auto alloc = [&](size_t bytes) -> void* {
        void* p = ws + off;
        off += (bytes + 255) & ~(size_t)255;
        return p;
    };
    int* perm  = (int*)alloc((size_t)NDIR*LL*4);
    int* rank  = (int*)alloc((size_t)NDIR*LL*4);
    float* x   = (float*)alloc((size_t)NDIR*LL*DD0*4);
    unsigned short* xnh = (unsigned short*)alloc((size_t)NDIR*LL*DD0*2);
    unsigned short* xnl = (unsigned short*)alloc((size_t)NDIR*LL*DD0*2);
    float* zx  = (float*)alloc((size_t)NDIR*LL*DIN*4);
    float* xc  = (float*)alloc((size_t)NDIR*LL*CONV_DIM*4);
    float* dt  = (float*)alloc((size_t)NDIR*LL*HH*4);
    float* dA  = (float*)alloc((size_t)NDIR*LL*HH*4);
    float* ysb = (float*)alloc((size_t)NDIR*LL*DI*4);
    unsigned short* uh = (unsigned short*)alloc((size_t)NDIR*LL*DI*2);
    unsigned short* ul = (unsigned short*)alloc((size_t)NDIR*LL*DI*2);
    float* cstate = (float*)alloc((size_t)NDIR*NC*HH*PP*NN*4);
    float* cumdec = (float*)alloc((size_t)NDIR*LL*HH*4);
    unsigned short* WinTh  = (unsigned short*)alloc((size_t)NDIR*NL*DIN*DD0*2);
    unsigned short* WinTl  = (unsigned short*)alloc((size_t)NDIR*NL*DIN*DD0*2);
    unsigned short* WoutTh = (unsigned short*)alloc((size_t)NDIR*NL*DD0*DI*2);
    unsigned short* WoutTl = (unsigned short*)alloc((size_t)NDIR*NL*DD0*DI*2);
    unsigned short* fWTh   = (unsigned short*)alloc((size_t)DD0*(NDIR*DD0)*2);
    unsigned short* fWTl   = (unsigned short*)alloc((size_t)DD0*(NDIR*DD0)*2);
    // alias md/mdn onto the (dead by then) uh/ul region
    float* md = (float*)uh;                                   // 6*1024*512*2 = 1024*1536*4 bytes
    unsigned short* mdnh = (unsigned short*)ul;               // 1024*1536*2
    unsigned short* mdnl = mdnh + (size_t)LL*(NDIR*DD0);      // 1024*1536*2
    (void)ws_size;

    sort_kernel<<<NDIR, 1024, 0, stream>>>(coords, perm, rank);
    gather_kernel<<<dim3(LL, NDIR), 256, 0, stream>>>(vectors, perm, x);

    // weight transpose + split (once per launch)
    tsplit_kernel<<<dim3((DIN+31)/32, DD0/32, NDIR*NL), 256, 0, stream>>>(Win, WinTh, WinTl, DD0, DIN);
    tsplit_kernel<<<dim3(DD0/32, DI/32, NDIR*NL), 256, 0, stream>>>(Wout, WoutTh, WoutTl, DI, DD0);
    tsplit_kernel<<<dim3(DD0/32, (NDIR*DD0)/32, 1), 256, 0, stream>>>(fuse_W, fWTh, fWTl, NDIR*DD0, DD0);

    for (int l = 0; l < NL; ++l) {
        ln_split<<<dim3(LL, NDIR), 256, 0, stream>>>(x, xnh, xnl, ln_g + l*DD0, ln_b + l*DD0,
                                                     DD0, LL, NL*DD0);
        mfma_gemm<0><<<dim3((DIN+63)/64, LL/128, NDIR), 256, 0, stream>>>(
            xnh, xnl, WinTh + (size_t)l*DIN*DD0, WinTl + (size_t)l*DIN*DD0, zx,
            DIN, DD0, (size_t)LL*DD0, (size_t)NL*DIN*DD0, (size_t)LL*DIN, nullptr);
        conv_kernel<<<dim3(LL, NDIR), 256, 0, stream>>>(zx, conv_w, conv_b, dt_bias, A_log,
                                                        xc, dt, dA, l);
        scan_pass1<<<NDIR*HH*NC, 256, 0, stream>>>(xc, dt, dA, ysb, cstate, cumdec);
        scan_pass2<<<NDIR*HH, 256, 0, stream>>>(cstate, cumdec);
        scan_pass3<<<NDIR*HH*NC, 256, 0, stream>>>(xc, cumdec, cstate, ysb);
        gate_rms<<<dim3(LL, NDIR), 256, 0, stream>>>(ysb, xc, zx, Dp, rms_g, uh, ul, l);
        mfma_gemm<1><<<dim3(DD0/64, LL/128, NDIR), 256, 0, stream>>>(
            uh, ul, WoutTh + (size_t)l*DD0*DI, WoutTl + (size_t)l*DD0*DI, x,
            DD0, DI, (size_t)LL*DI, (size_t)NL*DD0*DI, (size_t)LL*DD0, nullptr);
    }

    concat_kernel<<<dim3(LL, NDIR), 256, 0, stream>>>(x, rank, md);
    ln_split<<<dim3(LL, 1), 256, 0, stream>>>(md, mdnh, mdnl, fuse_ln_g, fuse_ln_b,
                                              NDIR*DD0, LL, 0);
    mfma_gemm<2><<<dim3(DD0/64, LL/128, 1), 256, 0, stream>>>(
        mdnh, mdnl, fWTh, fWTl, out, DD0, NDIR*DD0, 0, 0, 0, fuse_b);
}

// Round 4
// 379.566 us; speedup vs baseline: 3.6605x; 1.1299x over previous
//
#include <hip/hip_runtime.h>
#include <hip/hip_bf16.h>
#include <cstddef>

// Problem constants
#define LL 1024
#define DD0 256
#define NDIR 6
#define NL 2
#define HH 8
#define PP 64
#define NN 32
#define KK 4
#define DI 512           // 2*D
#define DIN 1096         // 2*DI + 2*N + H
#define CONV_DIM 576     // DI + 2*N

// chunked scan config
#define QC 32            // chunk length
#define NC 32            // LL / QC
#define NCSH 5           // log2(NC)

__constant__ int c_ord[6][3] = {{0,1,2},{0,2,1},{1,0,2},{1,2,0},{2,0,1},{2,1,0}};

typedef __attribute__((ext_vector_type(8))) short bf16x8;
typedef __attribute__((ext_vector_type(4))) float f32x4;

// ---------------- helpers ----------------
__device__ inline float blockReduceSum256(float v) {
    __shared__ float sred[4];
#pragma unroll
    for (int off = 1; off < 64; off <<= 1) v += __shfl_xor(v, off);
    int lane = threadIdx.x & 63, w = threadIdx.x >> 6;
    __syncthreads();               // protect sred from a previous call
    if (lane == 0) sred[w] = v;
    __syncthreads();
    return sred[0] + sred[1] + sred[2] + sred[3];
}

__device__ inline float siluf(float x) { return x / (1.f + expf(-x)); }

// round-to-nearest-even fp32 -> bf16 bits
__device__ inline unsigned short bf16_rn(float x) {
    unsigned u = __float_as_uint(x);
    unsigned r = (u + 0x7fffu + ((u >> 16) & 1u)) >> 16;
    return (unsigned short)r;
}
__device__ inline float bf16_to_f(unsigned short h) {
    return __uint_as_float(((unsigned)h) << 16);
}

// ---------------- sort (lexsort via rank counting) ----------------
__global__ __launch_bounds__(1024)
void sort_kernel(const int* __restrict__ coords, int* __restrict__ perm, int* __restrict__ rank) {
    int d = blockIdx.x;
    int i = threadIdx.x;
    __shared__ unsigned keys[LL];
    int a0 = c_ord[d][0], a1 = c_ord[d][1], a2 = c_ord[d][2];
    unsigned c0 = (unsigned)coords[i*4 + a0];
    unsigned c1 = (unsigned)coords[i*4 + a1];
    unsigned c2 = (unsigned)coords[i*4 + a2];
    unsigned key = (c0 << 22) | (c1 << 16) | (c2 << 10) | (unsigned)i;
    keys[i] = key;
    __syncthreads();
    int r = 0;
    for (int j = 0; j < LL; ++j) r += (keys[j] < key) ? 1 : 0;
    perm[d*LL + r] = i;
    rank[d*LL + i] = r;
}

// ---------------- gather x = vectors[perm] ----------------
__global__ __launch_bounds__(256)
void gather_kernel(const float* __restrict__ vectors, const int* __restrict__ perm,
                   float* __restrict__ x) {
    int t = blockIdx.x, d = blockIdx.y, c = threadIdx.x;
    int src = perm[d*LL + t];
    x[((size_t)d*LL + t)*DD0 + c] = vectors[(size_t)src*DD0 + c];
}

// ---------------- layernorm -> bf16 hi/lo split ----------------
__global__ __launch_bounds__(256)
void ln_split(const float* __restrict__ X, unsigned short* __restrict__ Yh,
              unsigned short* __restrict__ Yl,
              const float* __restrict__ g, const float* __restrict__ b,
              int dd, int rowsPerDir, int gstride) {
    int t = blockIdx.x, d = blockIdx.y;
    const float* xr = X + ((size_t)d*rowsPerDir + t)*dd;
    unsigned short* yh = Yh + ((size_t)d*rowsPerDir + t)*dd;
    unsigned short* yl = Yl + ((size_t)d*rowsPerDir + t)*dd;
    const float* gr = g + (size_t)d*gstride;
    const float* br = b + (size_t)d*gstride;
    float v[6];
    float s = 0.f, s2 = 0.f;
    int cnt = 0;
    for (int c = threadIdx.x; c < dd; c += 256) {
        float xv = xr[c];
        v[cnt++] = xv;
        s += xv; s2 += xv*xv;
    }
    float tot = blockReduceSum256(s);
    float tot2 = blockReduceSum256(s2);
    float mu = tot / dd;
    float var = tot2 / dd - mu*mu;
    float inv = rsqrtf(var + 1e-5f);
    cnt = 0;
    for (int c = threadIdx.x; c < dd; c += 256) {
        float yv = (v[cnt++] - mu) * inv * gr[c] + br[c];
        unsigned short h = bf16_rn(yv);
        yh[c] = h;
        yl[c] = bf16_rn(yv - bf16_to_f(h));
    }
}

// ---------------- tiled transpose + bf16 hi/lo split for weights ----------------
// W: [Kd][Nd] fp32 (batched, stride Kd*Nd) -> Th/Tl: [Nd][Kd] bf16 bits
__global__ __launch_bounds__(256)
void tsplit_kernel(const float* __restrict__ W, unsigned short* __restrict__ Th,
                   unsigned short* __restrict__ Tl, int Kd, int Nd) {
    __shared__ float tile[32][33];
    int j0 = blockIdx.x * 32;   // N
    int i0 = blockIdx.y * 32;   // K
    int c = threadIdx.x & 31, r8 = threadIdx.x >> 5;
    const float* Wz = W + (size_t)blockIdx.z * Kd * Nd;
    unsigned short* Thz = Th + (size_t)blockIdx.z * Nd * Kd;
    unsigned short* Tlz = Tl + (size_t)blockIdx.z * Nd * Kd;
#pragma unroll
    for (int s = 0; s < 4; ++s) {
        int i = i0 + r8 + s*8;
        tile[r8 + s*8][c] = (i < Kd && (j0 + c) < Nd) ? Wz[(size_t)i*Nd + j0 + c] : 0.f;
    }
    __syncthreads();
#pragma unroll
    for (int s = 0; s < 4; ++s) {
        int j = j0 + r8 + s*8;   // output row (n)
        int i = i0 + c;          // output col (k)
        if (j < Nd && i < Kd) {
            float x = tile[c][r8 + s*8];
            unsigned short h = bf16_rn(x);
            Thz[(size_t)j*Kd + i] = h;
            Tlz[(size_t)j*Kd + i] = bf16_rn(x - bf16_to_f(h));
        }
    }
}

// ---------------- split-precision MFMA GEMM, 2-deep prefetch pipeline ----------------
// C = A@B computed as Ah*Bh + Ah*Bl + Al*Bh  (fp32 accumulate)
// A: [M][K] bf16-bits hi/lo (row-major, k contiguous)
// B: [N][K] bf16-bits hi/lo (TRANSPOSED weights, k contiguous)
// Block tile BM x 64 (BM = 128 or 64), 4 waves (2x2), 16x16x32 MFMA.
// Register-staged prefetch 2 K-tiles ahead, double-buffered LDS, one barrier/K-step.
// MODE 0: C = AB ; MODE 1: C += AB ; MODE 2: C = gelu(AB + bias)
template<int MODE, int BM>
__global__ __launch_bounds__(256)
void mfma_gemm(const unsigned short* __restrict__ Ahg, const unsigned short* __restrict__ Alg,
               const unsigned short* __restrict__ Bhg, const unsigned short* __restrict__ Blg,
               float* __restrict__ Cg, int N, int K,
               size_t sA, size_t sB, size_t sC, const float* __restrict__ bias) {
    constexpr int MF = BM / 32;          // m-fragments per wave
    __shared__ unsigned short AhS[2][BM][40];
    __shared__ unsigned short AlS[2][BM][40];
    __shared__ unsigned short BhS[2][64][40];
    __shared__ unsigned short BlS[2][64][40];
    const unsigned short* Azh = Ahg + (size_t)blockIdx.z * sA;
    const unsigned short* Azl = Alg + (size_t)blockIdx.z * sA;
    const unsigned short* Bzh = Bhg + (size_t)blockIdx.z * sB;
    const unsigned short* Bzl = Blg + (size_t)blockIdx.z * sB;
    float* Cz = Cg + (size_t)blockIdx.z * sC;
    int row0 = blockIdx.y * BM;
    int col0 = blockIdx.x * 64;
    int tid = threadIdx.x;
    int lane = tid & 63, wid = tid >> 6;
    int mbase = (wid >> 1) * (BM/2), nbase = (wid & 1) * 32;
    int lr = lane & 15, lk = (lane >> 4) * 8;

    // staging thread mapping
    int ar0 = tid >> 2;          // A row (and +64 for BM=128)
    int ar1 = 64 + (tid >> 2);
    int ac  = (tid & 3) * 8;
    int brow = tid >> 2;         // B staging row = output col
    int bc8 = (tid & 3) * 8;
    bool bvalid = (col0 + brow) < N;
    const uint4 z4 = {0u,0u,0u,0u};

    f32x4 acc[MF][2];
#pragma unroll
    for (int m = 0; m < MF; ++m)
#pragma unroll
        for (int n = 0; n < 2; ++n) acc[m][n] = (f32x4){0.f, 0.f, 0.f, 0.f};

    // two named register sets (rule: no runtime-indexed reg arrays)
    uint4 s0a0, s0a1, s0l0, s0l1, s0bh, s0bl;
    uint4 s1a0, s1a1, s1l0, s1l1, s1bh, s1bl;

#define LOAD_TILE(Ra0,Ra1,Rl0,Rl1,Rbh,Rbl,kt) do {                          \
        size_t ka = (size_t)(kt) * 32;                                       \
        size_t g0 = (size_t)(row0 + ar0)*K + ka + ac;                        \
        Ra0 = *(const uint4*)(Azh + g0);                                     \
        Rl0 = *(const uint4*)(Azl + g0);                                     \
        if (BM == 128) {                                                     \
            size_t g1 = (size_t)(row0 + ar1)*K + ka + ac;                    \
            Ra1 = *(const uint4*)(Azh + g1);                                 \
            Rl1 = *(const uint4*)(Azl + g1);                                 \
        }                                                                    \
        if (bvalid) {                                                        \
            size_t gb = (size_t)(col0 + brow)*K + ka + bc8;                  \
            Rbh = *(const uint4*)(Bzh + gb);                                 \
            Rbl = *(const uint4*)(Bzl + gb);                                 \
        } else { Rbh = z4; Rbl = z4; }                                       \
    } while (0)

#define WRITE_TILE(buf,Ra0,Ra1,Rl0,Rl1,Rbh,Rbl) do {                         \
        *(uint4*)&AhS[buf][ar0][ac] = Ra0;                                   \
        *(uint4*)&AlS[buf][ar0][ac] = Rl0;                                   \
        if (BM == 128) {                                                     \
            *(uint4*)&AhS[buf][ar1 & (BM-1)][ac] = Ra1;                      \
            *(uint4*)&AlS[buf][ar1 & (BM-1)][ac] = Rl1;                      \
        }                                                                    \
        *(uint4*)&BhS[buf][brow][bc8] = Rbh;                                 \
        *(uint4*)&BlS[buf][brow][bc8] = Rbl;                                 \
    } while (0)

#define COMPUTE(buf) do {                                                    \
        bf16x8 afh[MF], afl[MF], bfh[2], bfl[2];                             \
        _Pragma("unroll")                                                    \
        for (int mf = 0; mf < MF; ++mf) {                                    \
            afh[mf] = *(const bf16x8*)&AhS[buf][mbase + mf*16 + lr][lk];     \
            afl[mf] = *(const bf16x8*)&AlS[buf][mbase + mf*16 + lr][lk];     \
        }                                                                    \
        _Pragma("unroll")                                                    \
        for (int nf = 0; nf < 2; ++nf) {                                     \
            bfh[nf] = *(const bf16x8*)&BhS[buf][nbase + nf*16 + lr][lk];     \
            bfl[nf] = *(const bf16x8*)&BlS[buf][nbase + nf*16 + lr][lk];     \
        }                                                                    \
        _Pragma("unroll")                                                    \
        for (int mf = 0; mf < MF; ++mf)                                      \
            _Pragma("unroll")                                                \
            for (int nf = 0; nf < 2; ++nf) {                                 \
                acc[mf][nf] = __builtin_amdgcn_mfma_f32_16x16x32_bf16(afh[mf], bfh[nf], acc[mf][nf], 0, 0, 0); \
                acc[mf][nf] = __builtin_amdgcn_mfma_f32_16x16x32_bf16(afh[mf], bfl[nf], acc[mf][nf], 0, 0, 0); \
                acc[mf][nf] = __builtin_amdgcn_mfma_f32_16x16x32_bf16(afl[mf], bfh[nf], acc[mf][nf], 0, 0, 0); \
            }                                                                \
    } while (0)

    int nt = K >> 5;   // # of 32-wide K-tiles; always even here (8,16,48)

    // prologue: tiles 0 and 1 in flight; write tile 0 to LDS buf0
    LOAD_TILE(s0a0, s0a1, s0l0, s0l1, s0bh, s0bl, 0);
    LOAD_TILE(s1a0, s1a1, s1l0, s1l1, s1bh, s1bl, 1);
    WRITE_TILE(0, s0a0, s0a1, s0l0, s0l1, s0bh, s0bl);   // auto vmcnt waits set0 only
    __syncthreads();

    for (int t = 0; t < nt; t += 2) {
        // even step: compute tile t from buf0; set1 holds tile t+1
        if (t + 2 < nt) LOAD_TILE(s0a0, s0a1, s0l0, s0l1, s0bh, s0bl, t + 2);
        COMPUTE(0);
        WRITE_TILE(1, s1a0, s1a1, s1l0, s1l1, s1bh, s1bl);
        __syncthreads();
        // odd step: compute tile t+1 from buf1; set0 holds tile t+2
        if (t + 3 < nt) LOAD_TILE(s1a0, s1a1, s1l0, s1l1, s1bh, s1bl, t + 3);
        COMPUTE(1);
        if (t + 2 < nt) WRITE_TILE(0, s0a0, s0a1, s0l0, s0l1, s0bh, s0bl);
        __syncthreads();
    }

#undef LOAD_TILE
#undef WRITE_TILE
#undef COMPUTE

    // epilogue: C/D layout col = lane&15, row = (lane>>4)*4 + reg
    int crb = (lane >> 4) * 4;
    int cco = lane & 15;
#pragma unroll
    for (int mf = 0; mf < MF; ++mf) {
#pragma unroll
        for (int nf = 0; nf < 2; ++nf) {
            int col = col0 + nbase + nf*16 + cco;
            if (col < N) {
#pragma unroll
                for (int r = 0; r < 4; ++r) {
                    int row = row0 + mbase + mf*16 + crb + r;
                    size_t o = (size_t)row*N + col;
                    float vv = acc[mf][nf][r];
                    if (MODE == 0) Cz[o] = vv;
                    else if (MODE == 1) Cz[o] += vv;
                    else {
                        vv += bias[col];
                        Cz[o] = 0.5f * vv * (1.f + erff(vv * 0.70710678118654752f));
                    }
                }
            }
        }
    }
}

// ---------------- causal depthwise conv (K=4) + silu, and dt/dA ----------------
__global__ __launch_bounds__(256)
void conv_kernel(const float* __restrict__ zx, const float* __restrict__ conv_w,
                 const float* __restrict__ conv_b, const float* __restrict__ dt_bias,
                 const float* __restrict__ A_log, float* __restrict__ xc,
                 float* __restrict__ dt, float* __restrict__ dA, int layer) {
    int t = blockIdx.x, d = blockIdx.y;
    const float* Z = zx + ((size_t)d*LL)*DIN;
    const float* w = conv_w + (size_t)(d*NL + layer)*CONV_DIM*KK;
    const float* b = conv_b + (size_t)(d*NL + layer)*CONV_DIM;
    float* outr = xc + ((size_t)d*LL + t)*CONV_DIM;
    for (int c = threadIdx.x; c < CONV_DIM; c += 256) {
        float acc = b[c];
#pragma unroll
        for (int j = 0; j < KK; ++j) {
            int tt = t - (KK-1) + j;
            if (tt >= 0) acc += Z[(size_t)tt*DIN + DI + c] * w[c*KK + j];
        }
        outr[c] = siluf(acc);
    }
    if (threadIdx.x < HH) {
        int hh = threadIdx.x;
        float v = Z[(size_t)t*DIN + (DIN - HH) + hh] + dt_bias[(d*NL + layer)*HH + hh];
        float sp = (v > 20.f) ? v : log1pf(expf(v));
        dt[((size_t)d*LL + t)*HH + hh] = sp;
        dA[((size_t)d*LL + t)*HH + hh] = expf(-expf(A_log[(d*NL + layer)*HH + hh]) * sp);
    }
}

// ---------------- chunked selective scan (3-pass, exact reassociation) ----------------
__global__ __launch_bounds__(256)
void scan_pass1(const float* __restrict__ xc, const float* __restrict__ dtA,
                const float* __restrict__ dAA, float* __restrict__ ys,
                float* __restrict__ cstate, float* __restrict__ cumdec) {
    int bid = blockIdx.x;
    int c = bid & (NC - 1);
    int hd = bid >> NCSH;
    int d = hd >> 3, h = hd & 7;
    int tid = threadIdx.x;
    int p = tid >> 2, g = tid & 3, n0 = g << 3;
    int t0 = c * QC;
    const float* xcd = xc + (size_t)d*LL*CONV_DIM;
    const float* dtd = dtA + (size_t)d*LL*HH + h;
    const float* dAd = dAA + (size_t)d*LL*HH + h;
    float* ysd = ys + (size_t)d*LL*DI + h*PP + p;
    float* cdd = cumdec + (size_t)d*LL*HH + h;

    __shared__ float sdt[QC];
    __shared__ float sdA[QC];
    if (tid < QC) sdt[tid] = dtd[(size_t)(t0 + tid)*HH];
    else if (tid < 2*QC) sdA[tid - QC] = dAd[(size_t)(t0 + tid - QC)*HH];
    __syncthreads();

    float hs[8];
#pragma unroll
    for (int j = 0; j < 8; ++j) hs[j] = 0.f;
    float cum = 1.f;

    const float* row = xcd + (size_t)t0*CONV_DIM;
    float xv = row[h*PP + p];
    float4 b0 = *(const float4*)(row + DI + n0);
    float4 b1 = *(const float4*)(row + DI + n0 + 4);
    float4 c0 = *(const float4*)(row + DI + NN + n0);
    float4 c1 = *(const float4*)(row + DI + NN + n0 + 4);

    for (int tt = 0; tt < QC; ++tt) {
        float nxv = 0.f;
        float4 nb0 = {0,0,0,0}, nb1 = {0,0,0,0}, nc0 = {0,0,0,0}, nc1 = {0,0,0,0};
        if (tt + 1 < QC) {
            const float* r2 = xcd + (size_t)(t0 + tt + 1)*CONV_DIM;
            nxv = r2[h*PP + p];
            nb0 = *(const float4*)(r2 + DI + n0);
            nb1 = *(const float4*)(r2 + DI + n0 + 4);
            nc0 = *(const float4*)(r2 + DI + NN + n0);
            nc1 = *(const float4*)(r2 + DI + NN + n0 + 4);
        }
        float dtv = sdt[tt], dAv = sdA[tt];
        float dtx = dtv * xv;
        float B[8] = {b0.x,b0.y,b0.z,b0.w,b1.x,b1.y,b1.z,b1.w};
        float Cv[8] = {c0.x,c0.y,c0.z,c0.w,c1.x,c1.y,c1.z,c1.w};
        float acc = 0.f;
#pragma unroll
        for (int j = 0; j < 8; ++j) {
            hs[j] = fmaf(dAv, hs[j], dtx * B[j]);
            acc = fmaf(hs[j], Cv[j], acc);
        }
        acc += __shfl_xor(acc, 1);
        acc += __shfl_xor(acc, 2);
        if (g == 0) ysd[(size_t)(t0 + tt)*DI] = acc;
        cum *= dAv;
        if (tid == 0) cdd[(size_t)(t0 + tt)*HH] = cum;
        xv = nxv; b0 = nb0; b1 = nb1; c0 = nc0; c1 = nc1;
    }

    float* cs = cstate + (((size_t)(d*NC + c)*HH + h)*PP + p)*NN + n0;
    float4 s0 = {hs[0], hs[1], hs[2], hs[3]};
    float4 s1 = {hs[4], hs[5], hs[6], hs[7]};
    *(float4*)cs = s0;
    *(float4*)(cs + 4) = s1;
}

__global__ __launch_bounds__(256)
void scan_pass2(float* __restrict__ cstate, const float* __restrict__ cumdec) {
    int hd = blockIdx.x;
    int d = hd >> 3, h = hd & 7;
    int tid = threadIdx.x;
    int p = tid >> 2, g = tid & 3, n0 = g << 3;
    float carry[8];
#pragma unroll
    for (int j = 0; j < 8; ++j) carry[j] = 0.f;
    for (int c = 0; c < NC; ++c) {
        float* cs = cstate + (((size_t)(d*NC + c)*HH + h)*PP + p)*NN + n0;
        float4 s0 = *(const float4*)cs;
        float4 s1 = *(const float4*)(cs + 4);
        float4 w0 = {carry[0], carry[1], carry[2], carry[3]};
        float4 w1 = {carry[4], carry[5], carry[6], carry[7]};
        *(float4*)cs = w0;
        *(float4*)(cs + 4) = w1;
        float dec = cumdec[((size_t)d*LL + (c*QC + QC - 1))*HH + h];
        float s[8] = {s0.x,s0.y,s0.z,s0.w,s1.x,s1.y,s1.z,s1.w};
#pragma unroll
        for (int j = 0; j < 8; ++j) carry[j] = fmaf(dec, carry[j], s[j]);
    }
}

__global__ __launch_bounds__(256)
void scan_pass3(const float* __restrict__ xc, const float* __restrict__ cumdec,
                const float* __restrict__ cstate, float* __restrict__ ys) {
    int bid = blockIdx.x;
    int c = bid & (NC - 1);
    if (c == 0) return;
    int hd = bid >> NCSH;
    int d = hd >> 3, h = hd & 7;
    int tid = threadIdx.x;
    int p = tid >> 2, g = tid & 3, n0 = g << 3;
    int t0 = c * QC;

    __shared__ float scd[QC];
    if (tid < QC) scd[tid] = cumdec[((size_t)d*LL + t0 + tid)*HH + h];

    const float* cs = cstate + (((size_t)(d*NC + c)*HH + h)*PP + p)*NN + n0;
    float4 h0 = *(const float4*)cs;
    float4 h1 = *(const float4*)(cs + 4);
    float hi[8] = {h0.x,h0.y,h0.z,h0.w,h1.x,h1.y,h1.z,h1.w};
    __syncthreads();

    const float* xcd = xc + (size_t)d*LL*CONV_DIM;
    float* ysd = ys + (size_t)d*LL*DI + h*PP + p;

    for (int tt = 0; tt < QC; ++tt) {
        int t = t0 + tt;
        const float* row = xcd + (size_t)t*CONV_DIM + DI + NN;
        float4 c0 = *(const float4*)(row + n0);
        float4 c1 = *(const float4*)(row + n0 + 4);
        float Cv[8] = {c0.x,c0.y,c0.z,c0.w,c1.x,c1.y,c1.z,c1.w};
        float acc = 0.f;
#pragma unroll
        for (int j = 0; j < 8; ++j) acc = fmaf(hi[j], Cv[j], acc);
        acc += __shfl_xor(acc, 1);
        acc += __shfl_xor(acc, 2);
        if (g == 0) ysd[(size_t)t*DI] += scd[tt] * acc;
    }
}

// ---------------- gating + RMSNorm -> bf16 hi/lo split ----------------
__global__ __launch_bounds__(256)
void gate_rms(const float* __restrict__ ys, const float* __restrict__ xc,
              const float* __restrict__ zx, const float* __restrict__ Dp,
              const float* __restrict__ rms_g, unsigned short* __restrict__ uh,
              unsigned short* __restrict__ ul, int layer) {
    int t = blockIdx.x, d = blockIdx.y;
    const float* ysr = ys + ((size_t)d*LL + t)*DI;
    const float* xcr = xc + ((size_t)d*LL + t)*CONV_DIM;
    const float* zr = zx + ((size_t)d*LL + t)*DIN;
    const float* Dpd = Dp + (d*NL + layer)*HH;
    const float* rg = rms_g + (size_t)(d*NL + layer)*DI;
    unsigned short* uhr = uh + ((size_t)d*LL + t)*DI;
    unsigned short* ulr = ul + ((size_t)d*LL + t)*DI;
    float vals[2];
    float ss = 0.f;
#pragma unroll
    for (int i = 0; i < 2; ++i) {
        int c = threadIdx.x + i*256;
        float xsv = xcr[c];
        int hh = c >> 6;
        float yv = ysr[c] + Dpd[hh] * xsv;
        float zv = zr[c];
        float uv = yv * siluf(zv);
        vals[i] = uv;
        ss += uv * uv;
    }
    float tot = blockReduceSum256(ss);
    float scale = rsqrtf(tot / DI + 1e-5f);
#pragma unroll
    for (int i = 0; i < 2; ++i) {
        int c = threadIdx.x + i*256;
        float uv = vals[i] * scale * rg[c];
        unsigned short h = bf16_rn(uv);
        uhr[c] = h;
        ulr[c] = bf16_rn(uv - bf16_to_f(h));
    }
}

// ---------------- concat (inverse permute + pack) ----------------
__global__ __launch_bounds__(256)
void concat_kernel(const float* __restrict__ x, const int* __restrict__ rank,
                   float* __restrict__ md) {
    int t = blockIdx.x, d = blockIdx.y, c = threadIdx.x;
    int r = rank[d*LL + t];
    md[(size_t)t*(NDIR*DD0) + d*DD0 + c] = x[((size_t)d*LL + r)*DD0 + c];
}

// ---------------- launch ----------------
extern "C" void kernel_launch(void* const* d_in, const int* in_sizes, int n_in,
                              void* d_out, int out_size, void* d_ws, size_t ws_size,
                              hipStream_t stream) {
    const float* vectors   = (const float*)d_in[0];
    const int*   coords    = (const int*)d_in[1];
    const float* ln_g      = (const float*)d_in[2];
    const float* ln_b      = (const float*)d_in[3];
    const float* Win       = (const float*)d_in[4];
    const float* conv_w    = (const float*)d_in[5];
    const float* conv_b    = (const float*)d_in[6];
    const float* dt_bias   = (const float*)d_in[7];
    const float* A_log     = (const float*)d_in[8];
    const float* Dp        = (const float*)d_in[9];
    const float* rms_g     = (const float*)d_in[10];
    const float* Wout      = (const float*)d_in[11];
    const float* fuse_ln_g = (const float*)d_in[12];
    const float* fuse_ln_b = (const float*)d_in[13];
    const float* fuse_W    = (const float*)d_in[14];
    const float* fuse_b    = (const float*)d_in[15];
    float* out = (float*)d_out;

    char* ws = (char*)d_ws;
    size_t off = 0;
    auto alloc = [&](size_t bytes) -> void* {
        void* p = ws + off;
        off += (bytes + 255) & ~(size_t)255;
        return p;
    };
    int* perm  = (int*)alloc((size_t)NDIR*LL*4);
    int* rank  = (int*)alloc((size_t)NDIR*LL*4);
    float* x   = (float*)alloc((size_t)NDIR*LL*DD0*4);
    unsigned short* xnh = (unsigned short*)alloc((size_t)NDIR*LL*DD0*2);
    unsigned short* xnl = (unsigned short*)alloc((size_t)NDIR*LL*DD0*2);
    float* zx  = (float*)alloc((size_t)NDIR*LL*DIN*4);
    float* xc  = (float*)alloc((size_t)NDIR*LL*CONV_DIM*4);
    float* dt  = (float*)alloc((size_t)NDIR*LL*HH*4);
    float* dA  = (float*)alloc((size_t)NDIR*LL*HH*4);
    float* ysb = (float*)alloc((size_t)NDIR*LL*DI*4);
    unsigned short* uh = (unsigned short*)alloc((size_t)NDIR*LL*DI*2);
    unsigned short* ul = (unsigned short*)alloc((size_t)NDIR*LL*DI*2);
    float* cstate = (float*)alloc((size_t)NDIR*NC*HH*PP*NN*4);
    float* cumdec = (float*)alloc((size_t)NDIR*LL*HH*4);
    unsigned short* WinTh  = (unsigned short*)alloc((size_t)NDIR*NL*DIN*DD0*2);
    unsigned short* WinTl  = (unsigned short*)alloc((size_t)NDIR*NL*DIN*DD0*2);
    unsigned short* WoutTh = (unsigned short*)alloc((size_t)NDIR*NL*DD0*DI*2);
    unsigned short* WoutTl = (unsigned short*)alloc((size_t)NDIR*NL*DD0*DI*2);
    unsigned short* fWTh   = (unsigned short*)alloc((size_t)DD0*(NDIR*DD0)*2);
    unsigned short* fWTl   = (unsigned short*)alloc((size_t)DD0*(NDIR*DD0)*2);
    // alias md/mdn onto the (dead by then) uh/ul region
    float* md = (float*)uh;                                   // 6*1024*512*2 = 1024*1536*4 bytes
    unsigned short* mdnh = (unsigned short*)ul;               // 1024*1536*2
    unsigned short* mdnl = mdnh + (size_t)LL*(NDIR*DD0);      // 1024*1536*2
    (void)ws_size;

    sort_kernel<<<NDIR, 1024, 0, stream>>>(coords, perm, rank);
    gather_kernel<<<dim3(LL, NDIR), 256, 0, stream>>>(vectors, perm, x);

    // weight transpose + split (once per launch)
    tsplit_kernel<<<dim3((DIN+31)/32, DD0/32, NDIR*NL), 256, 0, stream>>>(Win, WinTh, WinTl, DD0, DIN);
    tsplit_kernel<<<dim3(DD0/32, DI/32, NDIR*NL), 256, 0, stream>>>(Wout, WoutTh, WoutTl, DI, DD0);
    tsplit_kernel<<<dim3(DD0/32, (NDIR*DD0)/32, 1), 256, 0, stream>>>(fuse_W, fWTh, fWTl, NDIR*DD0, DD0);

    for (int l = 0; l < NL; ++l) {
        ln_split<<<dim3(LL, NDIR), 256, 0, stream>>>(x, xnh, xnl, ln_g + l*DD0, ln_b + l*DD0,
                                                     DD0, LL, NL*DD0);
        mfma_gemm<0,128><<<dim3((DIN+63)/64, LL/128, NDIR), 256, 0, stream>>>(
            xnh, xnl, WinTh + (size_t)l*DIN*DD0, WinTl + (size_t)l*DIN*DD0, zx,
            DIN, DD0, (size_t)LL*DD0, (size_t)NL*DIN*DD0, (size_t)LL*DIN, nullptr);
        conv_kernel<<<dim3(LL, NDIR), 256, 0, stream>>>(zx, conv_w, conv_b, dt_bias, A_log,
                                                        xc, dt, dA, l);
        scan_pass1<<<NDIR*HH*NC, 256, 0, stream>>>(xc, dt, dA, ysb, cstate, cumdec);
        scan_pass2<<<NDIR*HH, 256, 0, stream>>>(cstate, cumdec);
        scan_pass3<<<NDIR*HH*NC, 256, 0, stream>>>(xc, cumdec, cstate, ysb);
        gate_rms<<<dim3(LL, NDIR), 256, 0, stream>>>(ysb, xc, zx, Dp, rms_g, uh, ul, l);
        mfma_gemm<1,64><<<dim3(DD0/64, LL/64, NDIR), 256, 0, stream>>>(
            uh, ul, WoutTh + (size_t)l*DD0*DI, WoutTl + (size_t)l*DD0*DI, x,
            DD0, DI, (size_t)LL*DI, (size_t)NL*DD0*DI, (size_t)LL*DD0, nullptr);
    }

    concat_kernel<<<dim3(LL, NDIR), 256, 0, stream>>>(x, rank, md);
    ln_split<<<dim3(LL, 1), 256, 0, stream>>>(md, mdnh, mdnl, fuse_ln_g, fuse_ln_b,
                                              NDIR*DD0, LL, 0);
    mfma_gemm<2,64><<<dim3(DD0/64, LL/64, 1), 256, 0, stream>>>(
        mdnh, mdnl, fWTh, fWTl, out, DD0, NDIR*DD0, 0, 0, 0, fuse_b);
}

// Round 5
// 308.415 us; speedup vs baseline: 4.5050x; 1.2307x over previous
//
#include <hip/hip_runtime.h>
#include <hip/hip_bf16.h>
#include <cstddef>

// Problem constants
#define LL 1024
#define DD0 256
#define NDIR 6
#define NL 2
#define HH 8
#define PP 64
#define NN 32
#define KK 4
#define DI 512           // 2*D
#define DIN 1096         // 2*DI + 2*N + H
#define CONV_DIM 576     // DI + 2*N

// chunked scan config
#define QC 32            // chunk length
#define NC 32            // LL / QC
#define NCSH 5           // log2(NC)

__constant__ int c_ord[6][3] = {{0,1,2},{0,2,1},{1,0,2},{1,2,0},{2,0,1},{2,1,0}};

typedef __attribute__((ext_vector_type(8))) short bf16x8;
typedef __attribute__((ext_vector_type(4))) float f32x4;

// ---------------- helpers ----------------
__device__ inline float blockReduceSum256(float v) {
    __shared__ float sred[4];
#pragma unroll
    for (int off = 1; off < 64; off <<= 1) v += __shfl_xor(v, off);
    int lane = threadIdx.x & 63, w = threadIdx.x >> 6;
    __syncthreads();               // protect sred from a previous call
    if (lane == 0) sred[w] = v;
    __syncthreads();
    return sred[0] + sred[1] + sred[2] + sred[3];
}

__device__ inline float siluf(float x) { return x / (1.f + expf(-x)); }

// round-to-nearest-even fp32 -> bf16 bits
__device__ inline unsigned short bf16_rn(float x) {
    unsigned u = __float_as_uint(x);
    unsigned r = (u + 0x7fffu + ((u >> 16) & 1u)) >> 16;
    return (unsigned short)r;
}
__device__ inline float bf16_to_f(unsigned short h) {
    return __uint_as_float(((unsigned)h) << 16);
}

// ---------------- sort (lexsort via rank counting) ----------------
__global__ __launch_bounds__(1024)
void sort_kernel(const int* __restrict__ coords, int* __restrict__ perm, int* __restrict__ rank) {
    int d = blockIdx.x;
    int i = threadIdx.x;
    __shared__ unsigned keys[LL];
    int a0 = c_ord[d][0], a1 = c_ord[d][1], a2 = c_ord[d][2];
    unsigned c0 = (unsigned)coords[i*4 + a0];
    unsigned c1 = (unsigned)coords[i*4 + a1];
    unsigned c2 = (unsigned)coords[i*4 + a2];
    unsigned key = (c0 << 22) | (c1 << 16) | (c2 << 10) | (unsigned)i;
    keys[i] = key;
    __syncthreads();
    int r = 0;
    for (int j = 0; j < LL; ++j) r += (keys[j] < key) ? 1 : 0;
    perm[d*LL + r] = i;
    rank[d*LL + i] = r;
}

// ---------------- fused gather + layer-0 layernorm -> residual + bf16 hi/lo ----------------
__global__ __launch_bounds__(256)
void gather_ln(const float* __restrict__ vectors, const int* __restrict__ perm,
               float* __restrict__ x, unsigned short* __restrict__ Yh,
               unsigned short* __restrict__ Yl,
               const float* __restrict__ g, const float* __restrict__ b) {
    int t = blockIdx.x, d = blockIdx.y, c = threadIdx.x;
    int src = perm[d*LL + t];
    float xv = vectors[(size_t)src*DD0 + c];
    x[((size_t)d*LL + t)*DD0 + c] = xv;
    float s = blockReduceSum256(xv);
    float s2 = blockReduceSum256(xv*xv);
    float mu = s / DD0;
    float var = s2 / DD0 - mu*mu;
    float inv = rsqrtf(var + 1e-5f);
    const float* gr = g + (size_t)d*NL*DD0;
    const float* br = b + (size_t)d*NL*DD0;
    float yv = (xv - mu) * inv * gr[c] + br[c];
    unsigned short h = bf16_rn(yv);
    Yh[((size_t)d*LL + t)*DD0 + c] = h;
    Yl[((size_t)d*LL + t)*DD0 + c] = bf16_rn(yv - bf16_to_f(h));
}

// ---------------- layernorm -> bf16 hi/lo split (layer 1) ----------------
__global__ __launch_bounds__(256)
void ln_split(const float* __restrict__ X, unsigned short* __restrict__ Yh,
              unsigned short* __restrict__ Yl,
              const float* __restrict__ g, const float* __restrict__ b,
              int dd, int rowsPerDir, int gstride) {
    int t = blockIdx.x, d = blockIdx.y;
    const float* xr = X + ((size_t)d*rowsPerDir + t)*dd;
    unsigned short* yh = Yh + ((size_t)d*rowsPerDir + t)*dd;
    unsigned short* yl = Yl + ((size_t)d*rowsPerDir + t)*dd;
    const float* gr = g + (size_t)d*gstride;
    const float* br = b + (size_t)d*gstride;
    float v[6];
    float s = 0.f, s2 = 0.f;
    int cnt = 0;
    for (int c = threadIdx.x; c < dd; c += 256) {
        float xv = xr[c];
        v[cnt++] = xv;
        s += xv; s2 += xv*xv;
    }
    float tot = blockReduceSum256(s);
    float tot2 = blockReduceSum256(s2);
    float mu = tot / dd;
    float var = tot2 / dd - mu*mu;
    float inv = rsqrtf(var + 1e-5f);
    cnt = 0;
    for (int c = threadIdx.x; c < dd; c += 256) {
        float yv = (v[cnt++] - mu) * inv * gr[c] + br[c];
        unsigned short h = bf16_rn(yv);
        yh[c] = h;
        yl[c] = bf16_rn(yv - bf16_to_f(h));
    }
}

// ---------------- fused inverse-permute concat + fuse layernorm ----------------
__global__ __launch_bounds__(256)
void ln_concat(const float* __restrict__ x, const int* __restrict__ rank,
               unsigned short* __restrict__ Yh, unsigned short* __restrict__ Yl,
               const float* __restrict__ g, const float* __restrict__ b) {
    int t = blockIdx.x, tid = threadIdx.x;
    float v[NDIR];
    float s = 0.f, s2 = 0.f;
#pragma unroll
    for (int d = 0; d < NDIR; ++d) {
        int r = rank[d*LL + t];
        float xv = x[((size_t)d*LL + r)*DD0 + tid];
        v[d] = xv;
        s += xv; s2 += xv*xv;
    }
    float tot = blockReduceSum256(s);
    float tot2 = blockReduceSum256(s2);
    const int dd = NDIR*DD0;
    float mu = tot / dd;
    float var = tot2 / dd - mu*mu;
    float inv = rsqrtf(var + 1e-5f);
#pragma unroll
    for (int d = 0; d < NDIR; ++d) {
        int c = d*DD0 + tid;
        float yv = (v[d] - mu) * inv * g[c] + b[c];
        unsigned short h = bf16_rn(yv);
        Yh[(size_t)t*dd + c] = h;
        Yl[(size_t)t*dd + c] = bf16_rn(yv - bf16_to_f(h));
    }
}

// ---------------- tiled transpose + bf16 hi/lo split for weights ----------------
__global__ __launch_bounds__(256)
void tsplit_kernel(const float* __restrict__ W, unsigned short* __restrict__ Th,
                   unsigned short* __restrict__ Tl, int Kd, int Nd) {
    __shared__ float tile[32][33];
    int j0 = blockIdx.x * 32;   // N
    int i0 = blockIdx.y * 32;   // K
    int c = threadIdx.x & 31, r8 = threadIdx.x >> 5;
    const float* Wz = W + (size_t)blockIdx.z * Kd * Nd;
    unsigned short* Thz = Th + (size_t)blockIdx.z * Nd * Kd;
    unsigned short* Tlz = Tl + (size_t)blockIdx.z * Nd * Kd;
#pragma unroll
    for (int s = 0; s < 4; ++s) {
        int i = i0 + r8 + s*8;
        tile[r8 + s*8][c] = (i < Kd && (j0 + c) < Nd) ? Wz[(size_t)i*Nd + j0 + c] : 0.f;
    }
    __syncthreads();
#pragma unroll
    for (int s = 0; s < 4; ++s) {
        int j = j0 + r8 + s*8;   // output row (n)
        int i = i0 + c;          // output col (k)
        if (j < Nd && i < Kd) {
            float xv = tile[c][r8 + s*8];
            unsigned short h = bf16_rn(xv);
            Thz[(size_t)j*Kd + i] = h;
            Tlz[(size_t)j*Kd + i] = bf16_rn(xv - bf16_to_f(h));
        }
    }
}

// ---------------- split-precision MFMA GEMM, 2-deep prefetch pipeline ----------------
template<int MODE, int BM>
__global__ __launch_bounds__(256)
void mfma_gemm(const unsigned short* __restrict__ Ahg, const unsigned short* __restrict__ Alg,
               const unsigned short* __restrict__ Bhg, const unsigned short* __restrict__ Blg,
               float* __restrict__ Cg, int N, int K,
               size_t sA, size_t sB, size_t sC, const float* __restrict__ bias) {
    constexpr int MF = BM / 32;          // m-fragments per wave
    __shared__ unsigned short AhS[2][BM][40];
    __shared__ unsigned short AlS[2][BM][40];
    __shared__ unsigned short BhS[2][64][40];
    __shared__ unsigned short BlS[2][64][40];
    const unsigned short* Azh = Ahg + (size_t)blockIdx.z * sA;
    const unsigned short* Azl = Alg + (size_t)blockIdx.z * sA;
    const unsigned short* Bzh = Bhg + (size_t)blockIdx.z * sB;
    const unsigned short* Bzl = Blg + (size_t)blockIdx.z * sB;
    float* Cz = Cg + (size_t)blockIdx.z * sC;
    int row0 = blockIdx.y * BM;
    int col0 = blockIdx.x * 64;
    int tid = threadIdx.x;
    int lane = tid & 63, wid = tid >> 6;
    int mbase = (wid >> 1) * (BM/2), nbase = (wid & 1) * 32;
    int lr = lane & 15, lk = (lane >> 4) * 8;

    int ar0 = tid >> 2;
    int ar1 = 64 + (tid >> 2);
    int ac  = (tid & 3) * 8;
    int brow = tid >> 2;
    int bc8 = (tid & 3) * 8;
    bool bvalid = (col0 + brow) < N;
    const uint4 z4 = {0u,0u,0u,0u};

    f32x4 acc[MF][2];
#pragma unroll
    for (int m = 0; m < MF; ++m)
#pragma unroll
        for (int n = 0; n < 2; ++n) acc[m][n] = (f32x4){0.f, 0.f, 0.f, 0.f};

    uint4 s0a0, s0a1, s0l0, s0l1, s0bh, s0bl;
    uint4 s1a0, s1a1, s1l0, s1l1, s1bh, s1bl;

#define LOAD_TILE(Ra0,Ra1,Rl0,Rl1,Rbh,Rbl,kt) do {                          \
        size_t ka = (size_t)(kt) * 32;                                       \
        size_t g0 = (size_t)(row0 + ar0)*K + ka + ac;                        \
        Ra0 = *(const uint4*)(Azh + g0);                                     \
        Rl0 = *(const uint4*)(Azl + g0);                                     \
        if (BM == 128) {                                                     \
            size_t g1 = (size_t)(row0 + ar1)*K + ka + ac;                    \
            Ra1 = *(const uint4*)(Azh + g1);                                 \
            Rl1 = *(const uint4*)(Azl + g1);                                 \
        }                                                                    \
        if (bvalid) {                                                        \
            size_t gb = (size_t)(col0 + brow)*K + ka + bc8;                  \
            Rbh = *(const uint4*)(Bzh + gb);                                 \
            Rbl = *(const uint4*)(Bzl + gb);                                 \
        } else { Rbh = z4; Rbl = z4; }                                       \
    } while (0)

#define WRITE_TILE(buf,Ra0,Ra1,Rl0,Rl1,Rbh,Rbl) do {                         \
        *(uint4*)&AhS[buf][ar0][ac] = Ra0;                                   \
        *(uint4*)&AlS[buf][ar0][ac] = Rl0;                                   \
        if (BM == 128) {                                                     \
            *(uint4*)&AhS[buf][ar1 & (BM-1)][ac] = Ra1;                      \
            *(uint4*)&AlS[buf][ar1 & (BM-1)][ac] = Rl1;                      \
        }                                                                    \
        *(uint4*)&BhS[buf][brow][bc8] = Rbh;                                 \
        *(uint4*)&BlS[buf][brow][bc8] = Rbl;                                 \
    } while (0)

#define COMPUTE(buf) do {                                                    \
        bf16x8 afh[MF], afl[MF], bfh[2], bfl[2];                             \
        _Pragma("unroll")                                                    \
        for (int mf = 0; mf < MF; ++mf) {                                    \
            afh[mf] = *(const bf16x8*)&AhS[buf][mbase + mf*16 + lr][lk];     \
            afl[mf] = *(const bf16x8*)&AlS[buf][mbase + mf*16 + lr][lk];     \
        }                                                                    \
        _Pragma("unroll")                                                    \
        for (int nf = 0; nf < 2; ++nf) {                                     \
            bfh[nf] = *(const bf16x8*)&BhS[buf][nbase + nf*16 + lr][lk];     \
            bfl[nf] = *(const bf16x8*)&BlS[buf][nbase + nf*16 + lr][lk];     \
        }                                                                    \
        _Pragma("unroll")                                                    \
        for (int mf = 0; mf < MF; ++mf)                                      \
            _Pragma("unroll")                                                \
            for (int nf = 0; nf < 2; ++nf) {                                 \
                acc[mf][nf] = __builtin_amdgcn_mfma_f32_16x16x32_bf16(afh[mf], bfh[nf], acc[mf][nf], 0, 0, 0); \
                acc[mf][nf] = __builtin_amdgcn_mfma_f32_16x16x32_bf16(afh[mf], bfl[nf], acc[mf][nf], 0, 0, 0); \
                acc[mf][nf] = __builtin_amdgcn_mfma_f32_16x16x32_bf16(afl[mf], bfh[nf], acc[mf][nf], 0, 0, 0); \
            }                                                                \
    } while (0)

    int nt = K >> 5;

    LOAD_TILE(s0a0, s0a1, s0l0, s0l1, s0bh, s0bl, 0);
    LOAD_TILE(s1a0, s1a1, s1l0, s1l1, s1bh, s1bl, 1);
    WRITE_TILE(0, s0a0, s0a1, s0l0, s0l1, s0bh, s0bl);
    __syncthreads();

    for (int t = 0; t < nt; t += 2) {
        if (t + 2 < nt) LOAD_TILE(s0a0, s0a1, s0l0, s0l1, s0bh, s0bl, t + 2);
        COMPUTE(0);
        WRITE_TILE(1, s1a0, s1a1, s1l0, s1l1, s1bh, s1bl);
        __syncthreads();
        if (t + 3 < nt) LOAD_TILE(s1a0, s1a1, s1l0, s1l1, s1bh, s1bl, t + 3);
        COMPUTE(1);
        if (t + 2 < nt) WRITE_TILE(0, s0a0, s0a1, s0l0, s0l1, s0bh, s0bl);
        __syncthreads();
    }

#undef LOAD_TILE
#undef WRITE_TILE
#undef COMPUTE

    int crb = (lane >> 4) * 4;
    int cco = lane & 15;
#pragma unroll
    for (int mf = 0; mf < MF; ++mf) {
#pragma unroll
        for (int nf = 0; nf < 2; ++nf) {
            int col = col0 + nbase + nf*16 + cco;
            if (col < N) {
#pragma unroll
                for (int r = 0; r < 4; ++r) {
                    int row = row0 + mbase + mf*16 + crb + r;
                    size_t o = (size_t)row*N + col;
                    float vv = acc[mf][nf][r];
                    if (MODE == 0) Cz[o] = vv;
                    else if (MODE == 1) Cz[o] += vv;
                    else {
                        vv += bias[col];
                        Cz[o] = 0.5f * vv * (1.f + erff(vv * 0.70710678118654752f));
                    }
                }
            }
        }
    }
}

// ---------------- FUSED conv(K=4)+silu + chunk-local selective scan ----------------
// Block = (d, h, chunk). Computes silu(causal dwconv) for this block's slices
// directly from zx into LDS, then scans from LDS. Also emits:
//   xcx[d][t][h*64+p] (xs, for gate_rms), Cbuf[d][t][n] (h==0 only, for pass3),
//   cumdec, chunk-final state.
__global__ __launch_bounds__(256)
void conv_scan1(const float* __restrict__ zx, const float* __restrict__ conv_w,
                const float* __restrict__ conv_b, const float* __restrict__ dt_bias,
                const float* __restrict__ A_log, float* __restrict__ ys,
                float* __restrict__ xcx, float* __restrict__ Cbuf,
                float* __restrict__ cstate, float* __restrict__ cumdec, int layer) {
    int bid = blockIdx.x;
    int c = bid & (NC - 1);
    int hd = bid >> NCSH;
    int d = hd >> 3, h = hd & 7;
    int tid = threadIdx.x;
    int t0 = c * QC;

    __shared__ float sxc[QC][132];   // cols 0..63 = xs slice, 64..95 = B, 96..127 = C
    __shared__ float sdt[QC];
    __shared__ float sdA[QC];

    const float* Z = zx + (size_t)d*LL*DIN;

    // ---- phase A: conv for 128 cols x 32 t ----
    {
        int col = tid & 127;
        int half = tid >> 7;            // 2 halves x 16 t
        int tstart = t0 + half*16;
        int realc = (col < 64) ? (h*PP + col) : ((col < 96) ? (DI + (col-64)) : (DI + NN + (col-96)));
        int zxcol = DI + realc;
        const float* wr = conv_w + ((size_t)(d*NL + layer)*CONV_DIM + realc)*KK;
        float w0 = wr[0], w1 = wr[1], w2 = wr[2], w3 = wr[3];
        float bias = conv_b[(size_t)(d*NL + layer)*CONV_DIM + realc];
        float z0 = (tstart-3 >= 0) ? Z[(size_t)(tstart-3)*DIN + zxcol] : 0.f;
        float z1 = (tstart-2 >= 0) ? Z[(size_t)(tstart-2)*DIN + zxcol] : 0.f;
        float z2 = (tstart-1 >= 0) ? Z[(size_t)(tstart-1)*DIN + zxcol] : 0.f;
#pragma unroll
        for (int tt = 0; tt < 16; ++tt) {
            int t = tstart + tt;
            float z3 = Z[(size_t)t*DIN + zxcol];
            float acc = bias;
            acc = fmaf(z0, w0, acc);
            acc = fmaf(z1, w1, acc);
            acc = fmaf(z2, w2, acc);
            acc = fmaf(z3, w3, acc);
            sxc[half*16 + tt][col] = siluf(acc);
            z0 = z1; z1 = z2; z2 = z3;
        }
    }
    // ---- phase A2: dt / dA for this h ----
    if (tid < QC) {
        int t = t0 + tid;
        float v = Z[(size_t)t*DIN + (DIN - HH) + h] + dt_bias[(d*NL + layer)*HH + h];
        float sp = (v > 20.f) ? v : log1pf(expf(v));
        sdt[tid] = sp;
        sdA[tid] = expf(-expf(A_log[(d*NL + layer)*HH + h]) * sp);
    }
    __syncthreads();

    // ---- phase B: chunk-local scan from LDS ----
    int p = tid >> 2, g = tid & 3, n0 = g << 3;
    float* ysd = ys + (size_t)d*LL*DI + h*PP + p;
    float* cdd = cumdec + (size_t)d*LL*HH + h;
    float* xcd = xcx + (size_t)d*LL*DI + h*PP + p;
    float* Cbd = Cbuf + (size_t)d*LL*NN;

    float hs[8];
#pragma unroll
    for (int j = 0; j < 8; ++j) hs[j] = 0.f;
    float cum = 1.f;

    for (int tt = 0; tt < QC; ++tt) {
        float dtv = sdt[tt], dAv = sdA[tt];
        float xv = sxc[tt][p];
        float dtx = dtv * xv;
        float4 b0 = *(const float4*)&sxc[tt][64 + n0];
        float4 b1 = *(const float4*)&sxc[tt][64 + n0 + 4];
        float4 c0 = *(const float4*)&sxc[tt][96 + n0];
        float4 c1 = *(const float4*)&sxc[tt][96 + n0 + 4];
        float B[8] = {b0.x,b0.y,b0.z,b0.w,b1.x,b1.y,b1.z,b1.w};
        float Cv[8] = {c0.x,c0.y,c0.z,c0.w,c1.x,c1.y,c1.z,c1.w};
        float acc = 0.f;
#pragma unroll
        for (int j = 0; j < 8; ++j) {
            hs[j] = fmaf(dAv, hs[j], dtx * B[j]);
            acc = fmaf(hs[j], Cv[j], acc);
        }
        acc += __shfl_xor(acc, 1);
        acc += __shfl_xor(acc, 2);
        int t = t0 + tt;
        if (g == 0) ysd[(size_t)t*DI] = acc;
        else if (g == 1) xcd[(size_t)t*DI] = xv;          // xs copy for gate_rms
        else if (g == 2 && h == 0 && p < NN) Cbd[(size_t)t*NN + p] = sxc[tt][96 + p];
        cum *= dAv;
        if (tid == 0) cdd[(size_t)t*HH] = cum;
    }

    float* cs = cstate + (((size_t)(d*NC + c)*HH + h)*PP + p)*NN + n0;
    float4 s0 = {hs[0], hs[1], hs[2], hs[3]};
    float4 s1 = {hs[4], hs[5], hs[6], hs[7]};
    *(float4*)cs = s0;
    *(float4*)(cs + 4) = s1;
}

// ---------------- pass2: sequential fixup over chunk states ----------------
__global__ __launch_bounds__(256)
void scan_pass2(float* __restrict__ cstate, const float* __restrict__ cumdec) {
    int hd = blockIdx.x;
    int d = hd >> 3, h = hd & 7;
    int tid = threadIdx.x;
    int p = tid >> 2, g = tid & 3, n0 = g << 3;
    float carry[8];
#pragma unroll
    for (int j = 0; j < 8; ++j) carry[j] = 0.f;
    for (int c = 0; c < NC; ++c) {
        float* cs = cstate + (((size_t)(d*NC + c)*HH + h)*PP + p)*NN + n0;
        float4 s0 = *(const float4*)cs;
        float4 s1 = *(const float4*)(cs + 4);
        float4 w0 = {carry[0], carry[1], carry[2], carry[3]};
        float4 w1 = {carry[4], carry[5], carry[6], carry[7]};
        *(float4*)cs = w0;
        *(float4*)(cs + 4) = w1;
        float dec = cumdec[((size_t)d*LL + (c*QC + QC - 1))*HH + h];
        float s[8] = {s0.x,s0.y,s0.z,s0.w,s1.x,s1.y,s1.z,s1.w};
#pragma unroll
        for (int j = 0; j < 8; ++j) carry[j] = fmaf(dec, carry[j], s[j]);
    }
}

// ---------------- pass3: y[t] += cumdec[t] * (C[t] . h_init) ----------------
__global__ __launch_bounds__(256)
void scan_pass3(const float* __restrict__ Cbuf, const float* __restrict__ cumdec,
                const float* __restrict__ cstate, float* __restrict__ ys) {
    int bid = blockIdx.x;
    int c = bid & (NC - 1);
    if (c == 0) return;
    int hd = bid >> NCSH;
    int d = hd >> 3, h = hd & 7;
    int tid = threadIdx.x;
    int p = tid >> 2, g = tid & 3, n0 = g << 3;
    int t0 = c * QC;

    __shared__ float scd[QC];
    if (tid < QC) scd[tid] = cumdec[((size_t)d*LL + t0 + tid)*HH + h];

    const float* cs = cstate + (((size_t)(d*NC + c)*HH + h)*PP + p)*NN + n0;
    float4 h0 = *(const float4*)cs;
    float4 h1 = *(const float4*)(cs + 4);
    float hi[8] = {h0.x,h0.y,h0.z,h0.w,h1.x,h1.y,h1.z,h1.w};
    __syncthreads();

    const float* Cbd = Cbuf + (size_t)d*LL*NN;
    float* ysd = ys + (size_t)d*LL*DI + h*PP + p;

    for (int tt = 0; tt < QC; ++tt) {
        int t = t0 + tt;
        const float* row = Cbd + (size_t)t*NN;
        float4 c0 = *(const float4*)(row + n0);
        float4 c1 = *(const float4*)(row + n0 + 4);
        float Cv[8] = {c0.x,c0.y,c0.z,c0.w,c1.x,c1.y,c1.z,c1.w};
        float acc = 0.f;
#pragma unroll
        for (int j = 0; j < 8; ++j) acc = fmaf(hi[j], Cv[j], acc);
        acc += __shfl_xor(acc, 1);
        acc += __shfl_xor(acc, 2);
        if (g == 0) ysd[(size_t)t*DI] += scd[tt] * acc;
    }
}

// ---------------- gating + RMSNorm -> bf16 hi/lo split ----------------
__global__ __launch_bounds__(256)
void gate_rms(const float* __restrict__ ys, const float* __restrict__ xcx,
              const float* __restrict__ zx, const float* __restrict__ Dp,
              const float* __restrict__ rms_g, unsigned short* __restrict__ uh,
              unsigned short* __restrict__ ul, int layer) {
    int t = blockIdx.x, d = blockIdx.y;
    const float* ysr = ys + ((size_t)d*LL + t)*DI;
    const float* xcr = xcx + ((size_t)d*LL + t)*DI;
    const float* zr = zx + ((size_t)d*LL + t)*DIN;
    const float* Dpd = Dp + (d*NL + layer)*HH;
    const float* rg = rms_g + (size_t)(d*NL + layer)*DI;
    unsigned short* uhr = uh + ((size_t)d*LL + t)*DI;
    unsigned short* ulr = ul + ((size_t)d*LL + t)*DI;
    float vals[2];
    float ss = 0.f;
#pragma unroll
    for (int i = 0; i < 2; ++i) {
        int c = threadIdx.x + i*256;
        float xsv = xcr[c];
        int hh = c >> 6;
        float yv = ysr[c] + Dpd[hh] * xsv;
        float zv = zr[c];
        float uv = yv * siluf(zv);
        vals[i] = uv;
        ss += uv * uv;
    }
    float tot = blockReduceSum256(ss);
    float scale = rsqrtf(tot / DI + 1e-5f);
#pragma unroll
    for (int i = 0; i < 2; ++i) {
        int c = threadIdx.x + i*256;
        float uv = vals[i] * scale * rg[c];
        unsigned short h = bf16_rn(uv);
        uhr[c] = h;
        ulr[c] = bf16_rn(uv - bf16_to_f(h));
    }
}

// ---------------- launch ----------------
extern "C" void kernel_launch(void* const* d_in, const int* in_sizes, int n_in,
                              void* d_out, int out_size, void* d_ws, size_t ws_size,
                              hipStream_t stream) {
    const float* vectors   = (const float*)d_in[0];
    const int*   coords    = (const int*)d_in[1];
    const float* ln_g      = (const float*)d_in[2];
    const float* ln_b      = (const float*)d_in[3];
    const float* Win       = (const float*)d_in[4];
    const float* conv_w    = (const float*)d_in[5];
    const float* conv_b    = (const float*)d_in[6];
    const float* dt_bias   = (const float*)d_in[7];
    const float* A_log     = (const float*)d_in[8];
    const float* Dp        = (const float*)d_in[9];
    const float* rms_g     = (const float*)d_in[10];
    const float* Wout      = (const float*)d_in[11];
    const float* fuse_ln_g = (const float*)d_in[12];
    const float* fuse_ln_b = (const float*)d_in[13];
    const float* fuse_W    = (const float*)d_in[14];
    const float* fuse_b    = (const float*)d_in[15];
    float* out = (float*)d_out;

    char* ws = (char*)d_ws;
    size_t off = 0;
    auto alloc = [&](size_t bytes) -> void* {
        void* p = ws + off;
        off += (bytes + 255) & ~(size_t)255;
        return p;
    };
    int* perm  = (int*)alloc((size_t)NDIR*LL*4);
    int* rank  = (int*)alloc((size_t)NDIR*LL*4);
    float* x   = (float*)alloc((size_t)NDIR*LL*DD0*4);
    unsigned short* xnh = (unsigned short*)alloc((size_t)NDIR*LL*DD0*2);
    unsigned short* xnl = (unsigned short*)alloc((size_t)NDIR*LL*DD0*2);
    float* zx  = (float*)alloc((size_t)NDIR*LL*DIN*4);
    float* xcx = (float*)alloc((size_t)NDIR*LL*DI*4);
    float* Cbuf= (float*)alloc((size_t)NDIR*LL*NN*4);
    float* ysb = (float*)alloc((size_t)NDIR*LL*DI*4);
    unsigned short* uh = (unsigned short*)alloc((size_t)NDIR*LL*DI*2);
    unsigned short* ul = (unsigned short*)alloc((size_t)NDIR*LL*DI*2);
    float* cstate = (float*)alloc((size_t)NDIR*NC*HH*PP*NN*4);
    float* cumdec = (float*)alloc((size_t)NDIR*LL*HH*4);
    unsigned short* WinTh  = (unsigned short*)alloc((size_t)NDIR*NL*DIN*DD0*2);
    unsigned short* WinTl  = (unsigned short*)alloc((size_t)NDIR*NL*DIN*DD0*2);
    unsigned short* WoutTh = (unsigned short*)alloc((size_t)NDIR*NL*DD0*DI*2);
    unsigned short* WoutTl = (unsigned short*)alloc((size_t)NDIR*NL*DD0*DI*2);
    unsigned short* fWTh   = (unsigned short*)alloc((size_t)DD0*(NDIR*DD0)*2);
    unsigned short* fWTl   = (unsigned short*)alloc((size_t)DD0*(NDIR*DD0)*2);
    // mdn hi/lo aliased onto the (dead by then) uh/ul region
    unsigned short* mdnh = uh;                                // 1024*1536 shorts = 3.1MB
    unsigned short* mdnl = ul;                                // 1024*1536 shorts
    (void)ws_size;

    sort_kernel<<<NDIR, 1024, 0, stream>>>(coords, perm, rank);

    // weight transpose + split (once per launch)
    tsplit_kernel<<<dim3((DIN+31)/32, DD0/32, NDIR*NL), 256, 0, stream>>>(Win, WinTh, WinTl, DD0, DIN);
    tsplit_kernel<<<dim3(DD0/32, DI/32, NDIR*NL), 256, 0, stream>>>(Wout, WoutTh, WoutTl, DI, DD0);
    tsplit_kernel<<<dim3(DD0/32, (NDIR*DD0)/32, 1), 256, 0, stream>>>(fuse_W, fWTh, fWTl, NDIR*DD0, DD0);

    for (int l = 0; l < NL; ++l) {
        if (l == 0)
            gather_ln<<<dim3(LL, NDIR), 256, 0, stream>>>(vectors, perm, x, xnh, xnl, ln_g, ln_b);
        else
            ln_split<<<dim3(LL, NDIR), 256, 0, stream>>>(x, xnh, xnl, ln_g + l*DD0, ln_b + l*DD0,
                                                         DD0, LL, NL*DD0);
        mfma_gemm<0,128><<<dim3((DIN+63)/64, LL/128, NDIR), 256, 0, stream>>>(
            xnh, xnl, WinTh + (size_t)l*DIN*DD0, WinTl + (size_t)l*DIN*DD0, zx,
            DIN, DD0, (size_t)LL*DD0, (size_t)NL*DIN*DD0, (size_t)LL*DIN, nullptr);
        conv_scan1<<<NDIR*HH*NC, 256, 0, stream>>>(zx, conv_w, conv_b, dt_bias, A_log,
                                                   ysb, xcx, Cbuf, cstate, cumdec, l);
        scan_pass2<<<NDIR*HH, 256, 0, stream>>>(cstate, cumdec);
        scan_pass3<<<NDIR*HH*NC, 256, 0, stream>>>(Cbuf, cumdec, cstate, ysb);
        gate_rms<<<dim3(LL, NDIR), 256, 0, stream>>>(ysb, xcx, zx, Dp, rms_g, uh, ul, l);
        mfma_gemm<1,64><<<dim3(DD0/64, LL/64, NDIR), 256, 0, stream>>>(
            uh, ul, WoutTh + (size_t)l*DD0*DI, WoutTl + (size_t)l*DD0*DI, x,
            DD0, DI, (size_t)LL*DI, (size_t)NL*DD0*DI, (size_t)LL*DD0, nullptr);
    }

    ln_concat<<<LL, 256, 0, stream>>>(x, rank, mdnh, mdnl, fuse_ln_g, fuse_ln_b);
    mfma_gemm<2,64><<<dim3(DD0/64, LL/64, 1), 256, 0, stream>>>(
        mdnh, mdnl, fWTh, fWTl, out, DD0, NDIR*DD0, 0, 0, 0, fuse_b);
}

// Round 6
// 300.460 us; speedup vs baseline: 4.6242x; 1.0265x over previous
//
#include <hip/hip_runtime.h>
#include <hip/hip_bf16.h>
#include <cstddef>

// Problem constants
#define LL 1024
#define DD0 256
#define NDIR 6
#define NL 2
#define HH 8
#define PP 64
#define NN 32
#define KK 4
#define DI 512           // 2*D
#define DIN 1096         // 2*DI + 2*N + H
#define CONV_DIM 576     // DI + 2*N

// chunked scan config
#define QC 32            // chunk length
#define NC 32            // LL / QC
#define NCSH 5           // log2(NC)

__constant__ int c_ord[6][3] = {{0,1,2},{0,2,1},{1,0,2},{1,2,0},{2,0,1},{2,1,0}};

typedef __attribute__((ext_vector_type(8))) short bf16x8;
typedef __attribute__((ext_vector_type(4))) float f32x4;

// ---------------- helpers ----------------
__device__ inline float blockReduceSum256(float v) {
    __shared__ float sred[4];
#pragma unroll
    for (int off = 1; off < 64; off <<= 1) v += __shfl_xor(v, off);
    int lane = threadIdx.x & 63, w = threadIdx.x >> 6;
    __syncthreads();               // protect sred from a previous call
    if (lane == 0) sred[w] = v;
    __syncthreads();
    return sred[0] + sred[1] + sred[2] + sred[3];
}

__device__ inline float siluf(float x) { return x / (1.f + expf(-x)); }

// round-to-nearest-even fp32 -> bf16 bits
__device__ inline unsigned short bf16_rn(float x) {
    unsigned u = __float_as_uint(x);
    unsigned r = (u + 0x7fffu + ((u >> 16) & 1u)) >> 16;
    return (unsigned short)r;
}
__device__ inline float bf16_to_f(unsigned short h) {
    return __uint_as_float(((unsigned)h) << 16);
}

// ---------------- sort (lexsort via rank counting) ----------------
__global__ __launch_bounds__(1024)
void sort_kernel(const int* __restrict__ coords, int* __restrict__ perm, int* __restrict__ rank) {
    int d = blockIdx.x;
    int i = threadIdx.x;
    __shared__ unsigned keys[LL];
    int a0 = c_ord[d][0], a1 = c_ord[d][1], a2 = c_ord[d][2];
    unsigned c0 = (unsigned)coords[i*4 + a0];
    unsigned c1 = (unsigned)coords[i*4 + a1];
    unsigned c2 = (unsigned)coords[i*4 + a2];
    unsigned key = (c0 << 22) | (c1 << 16) | (c2 << 10) | (unsigned)i;
    keys[i] = key;
    __syncthreads();
    int r = 0;
    for (int j = 0; j < LL; ++j) r += (keys[j] < key) ? 1 : 0;
    perm[d*LL + r] = i;
    rank[d*LL + i] = r;
}

// ---------------- fused gather + layer-0 layernorm -> residual + bf16 hi/lo ----------------
__global__ __launch_bounds__(256)
void gather_ln(const float* __restrict__ vectors, const int* __restrict__ perm,
               float* __restrict__ x, unsigned short* __restrict__ Yh,
               unsigned short* __restrict__ Yl,
               const float* __restrict__ g, const float* __restrict__ b) {
    int t = blockIdx.x, d = blockIdx.y, c = threadIdx.x;
    int src = perm[d*LL + t];
    float xv = vectors[(size_t)src*DD0 + c];
    x[((size_t)d*LL + t)*DD0 + c] = xv;
    float s = blockReduceSum256(xv);
    float s2 = blockReduceSum256(xv*xv);
    float mu = s / DD0;
    float var = s2 / DD0 - mu*mu;
    float inv = rsqrtf(var + 1e-5f);
    const float* gr = g + (size_t)d*NL*DD0;
    const float* br = b + (size_t)d*NL*DD0;
    float yv = (xv - mu) * inv * gr[c] + br[c];
    unsigned short h = bf16_rn(yv);
    Yh[((size_t)d*LL + t)*DD0 + c] = h;
    Yl[((size_t)d*LL + t)*DD0 + c] = bf16_rn(yv - bf16_to_f(h));
}

// ---------------- layernorm -> bf16 hi/lo split (layer 1) ----------------
__global__ __launch_bounds__(256)
void ln_split(const float* __restrict__ X, unsigned short* __restrict__ Yh,
              unsigned short* __restrict__ Yl,
              const float* __restrict__ g, const float* __restrict__ b,
              int dd, int rowsPerDir, int gstride) {
    int t = blockIdx.x, d = blockIdx.y;
    const float* xr = X + ((size_t)d*rowsPerDir + t)*dd;
    unsigned short* yh = Yh + ((size_t)d*rowsPerDir + t)*dd;
    unsigned short* yl = Yl + ((size_t)d*rowsPerDir + t)*dd;
    const float* gr = g + (size_t)d*gstride;
    const float* br = b + (size_t)d*gstride;
    float v[6];
    float s = 0.f, s2 = 0.f;
    int cnt = 0;
    for (int c = threadIdx.x; c < dd; c += 256) {
        float xv = xr[c];
        v[cnt++] = xv;
        s += xv; s2 += xv*xv;
    }
    float tot = blockReduceSum256(s);
    float tot2 = blockReduceSum256(s2);
    float mu = tot / dd;
    float var = tot2 / dd - mu*mu;
    float inv = rsqrtf(var + 1e-5f);
    cnt = 0;
    for (int c = threadIdx.x; c < dd; c += 256) {
        float yv = (v[cnt++] - mu) * inv * gr[c] + br[c];
        unsigned short h = bf16_rn(yv);
        yh[c] = h;
        yl[c] = bf16_rn(yv - bf16_to_f(h));
    }
}

// ---------------- fused inverse-permute concat + fuse layernorm ----------------
__global__ __launch_bounds__(256)
void ln_concat(const float* __restrict__ x, const int* __restrict__ rank,
               unsigned short* __restrict__ Yh, unsigned short* __restrict__ Yl,
               const float* __restrict__ g, const float* __restrict__ b) {
    int t = blockIdx.x, tid = threadIdx.x;
    float v[NDIR];
    float s = 0.f, s2 = 0.f;
#pragma unroll
    for (int d = 0; d < NDIR; ++d) {
        int r = rank[d*LL + t];
        float xv = x[((size_t)d*LL + r)*DD0 + tid];
        v[d] = xv;
        s += xv; s2 += xv*xv;
    }
    float tot = blockReduceSum256(s);
    float tot2 = blockReduceSum256(s2);
    const int dd = NDIR*DD0;
    float mu = tot / dd;
    float var = tot2 / dd - mu*mu;
    float inv = rsqrtf(var + 1e-5f);
#pragma unroll
    for (int d = 0; d < NDIR; ++d) {
        int c = d*DD0 + tid;
        float yv = (v[d] - mu) * inv * g[c] + b[c];
        unsigned short h = bf16_rn(yv);
        Yh[(size_t)t*dd + c] = h;
        Yl[(size_t)t*dd + c] = bf16_rn(yv - bf16_to_f(h));
    }
}

// ---------------- tiled transpose + bf16 hi/lo split for weights ----------------
__global__ __launch_bounds__(256)
void tsplit_kernel(const float* __restrict__ W, unsigned short* __restrict__ Th,
                   unsigned short* __restrict__ Tl, int Kd, int Nd) {
    __shared__ float tile[32][33];
    int j0 = blockIdx.x * 32;   // N
    int i0 = blockIdx.y * 32;   // K
    int c = threadIdx.x & 31, r8 = threadIdx.x >> 5;
    const float* Wz = W + (size_t)blockIdx.z * Kd * Nd;
    unsigned short* Thz = Th + (size_t)blockIdx.z * Nd * Kd;
    unsigned short* Tlz = Tl + (size_t)blockIdx.z * Nd * Kd;
#pragma unroll
    for (int s = 0; s < 4; ++s) {
        int i = i0 + r8 + s*8;
        tile[r8 + s*8][c] = (i < Kd && (j0 + c) < Nd) ? Wz[(size_t)i*Nd + j0 + c] : 0.f;
    }
    __syncthreads();
#pragma unroll
    for (int s = 0; s < 4; ++s) {
        int j = j0 + r8 + s*8;   // output row (n)
        int i = i0 + c;          // output col (k)
        if (j < Nd && i < Kd) {
            float xv = tile[c][r8 + s*8];
            unsigned short h = bf16_rn(xv);
            Thz[(size_t)j*Kd + i] = h;
            Tlz[(size_t)j*Kd + i] = bf16_rn(xv - bf16_to_f(h));
        }
    }
}

// ---------------- split-precision MFMA GEMM, 2-deep prefetch pipeline ----------------
// All call sites use BM=64 now: 40KB LDS -> 4 blocks/CU (16 waves/CU) for
// latency hiding; we are latency-bound, not MFMA-issue-bound.
template<int MODE, int BM>
__global__ __launch_bounds__(256)
void mfma_gemm(const unsigned short* __restrict__ Ahg, const unsigned short* __restrict__ Alg,
               const unsigned short* __restrict__ Bhg, const unsigned short* __restrict__ Blg,
               float* __restrict__ Cg, int N, int K,
               size_t sA, size_t sB, size_t sC, const float* __restrict__ bias) {
    constexpr int MF = BM / 32;          // m-fragments per wave
    __shared__ unsigned short AhS[2][BM][40];
    __shared__ unsigned short AlS[2][BM][40];
    __shared__ unsigned short BhS[2][64][40];
    __shared__ unsigned short BlS[2][64][40];
    const unsigned short* Azh = Ahg + (size_t)blockIdx.z * sA;
    const unsigned short* Azl = Alg + (size_t)blockIdx.z * sA;
    const unsigned short* Bzh = Bhg + (size_t)blockIdx.z * sB;
    const unsigned short* Bzl = Blg + (size_t)blockIdx.z * sB;
    float* Cz = Cg + (size_t)blockIdx.z * sC;
    int row0 = blockIdx.y * BM;
    int col0 = blockIdx.x * 64;
    int tid = threadIdx.x;
    int lane = tid & 63, wid = tid >> 6;
    int mbase = (wid >> 1) * (BM/2), nbase = (wid & 1) * 32;
    int lr = lane & 15, lk = (lane >> 4) * 8;

    int ar0 = tid >> 2;
    int ar1 = 64 + (tid >> 2);
    int ac  = (tid & 3) * 8;
    int brow = tid >> 2;
    int bc8 = (tid & 3) * 8;
    bool bvalid = (col0 + brow) < N;
    const uint4 z4 = {0u,0u,0u,0u};

    f32x4 acc[MF][2];
#pragma unroll
    for (int m = 0; m < MF; ++m)
#pragma unroll
        for (int n = 0; n < 2; ++n) acc[m][n] = (f32x4){0.f, 0.f, 0.f, 0.f};

    uint4 s0a0, s0a1, s0l0, s0l1, s0bh, s0bl;
    uint4 s1a0, s1a1, s1l0, s1l1, s1bh, s1bl;

#define LOAD_TILE(Ra0,Ra1,Rl0,Rl1,Rbh,Rbl,kt) do {                          \
        size_t ka = (size_t)(kt) * 32;                                       \
        size_t g0 = (size_t)(row0 + ar0)*K + ka + ac;                        \
        Ra0 = *(const uint4*)(Azh + g0);                                     \
        Rl0 = *(const uint4*)(Azl + g0);                                     \
        if (BM == 128) {                                                     \
            size_t g1 = (size_t)(row0 + ar1)*K + ka + ac;                    \
            Ra1 = *(const uint4*)(Azh + g1);                                 \
            Rl1 = *(const uint4*)(Azl + g1);                                 \
        }                                                                    \
        if (bvalid) {                                                        \
            size_t gb = (size_t)(col0 + brow)*K + ka + bc8;                  \
            Rbh = *(const uint4*)(Bzh + gb);                                 \
            Rbl = *(const uint4*)(Bzl + gb);                                 \
        } else { Rbh = z4; Rbl = z4; }                                       \
    } while (0)

#define WRITE_TILE(buf,Ra0,Ra1,Rl0,Rl1,Rbh,Rbl) do {                         \
        *(uint4*)&AhS[buf][ar0][ac] = Ra0;                                   \
        *(uint4*)&AlS[buf][ar0][ac] = Rl0;                                   \
        if (BM == 128) {                                                     \
            *(uint4*)&AhS[buf][ar1 & (BM-1)][ac] = Ra1;                      \
            *(uint4*)&AlS[buf][ar1 & (BM-1)][ac] = Rl1;                      \
        }                                                                    \
        *(uint4*)&BhS[buf][brow][bc8] = Rbh;                                 \
        *(uint4*)&BlS[buf][brow][bc8] = Rbl;                                 \
    } while (0)

#define COMPUTE(buf) do {                                                    \
        bf16x8 afh[MF], afl[MF], bfh[2], bfl[2];                             \
        _Pragma("unroll")                                                    \
        for (int mf = 0; mf < MF; ++mf) {                                    \
            afh[mf] = *(const bf16x8*)&AhS[buf][mbase + mf*16 + lr][lk];     \
            afl[mf] = *(const bf16x8*)&AlS[buf][mbase + mf*16 + lr][lk];     \
        }                                                                    \
        _Pragma("unroll")                                                    \
        for (int nf = 0; nf < 2; ++nf) {                                     \
            bfh[nf] = *(const bf16x8*)&BhS[buf][nbase + nf*16 + lr][lk];     \
            bfl[nf] = *(const bf16x8*)&BlS[buf][nbase + nf*16 + lr][lk];     \
        }                                                                    \
        _Pragma("unroll")                                                    \
        for (int mf = 0; mf < MF; ++mf)                                      \
            _Pragma("unroll")                                                \
            for (int nf = 0; nf < 2; ++nf) {                                 \
                acc[mf][nf] = __builtin_amdgcn_mfma_f32_16x16x32_bf16(afh[mf], bfh[nf], acc[mf][nf], 0, 0, 0); \
                acc[mf][nf] = __builtin_amdgcn_mfma_f32_16x16x32_bf16(afh[mf], bfl[nf], acc[mf][nf], 0, 0, 0); \
                acc[mf][nf] = __builtin_amdgcn_mfma_f32_16x16x32_bf16(afl[mf], bfh[nf], acc[mf][nf], 0, 0, 0); \
            }                                                                \
    } while (0)

    int nt = K >> 5;

    LOAD_TILE(s0a0, s0a1, s0l0, s0l1, s0bh, s0bl, 0);
    LOAD_TILE(s1a0, s1a1, s1l0, s1l1, s1bh, s1bl, 1);
    WRITE_TILE(0, s0a0, s0a1, s0l0, s0l1, s0bh, s0bl);
    __syncthreads();

    for (int t = 0; t < nt; t += 2) {
        if (t + 2 < nt) LOAD_TILE(s0a0, s0a1, s0l0, s0l1, s0bh, s0bl, t + 2);
        COMPUTE(0);
        WRITE_TILE(1, s1a0, s1a1, s1l0, s1l1, s1bh, s1bl);
        __syncthreads();
        if (t + 3 < nt) LOAD_TILE(s1a0, s1a1, s1l0, s1l1, s1bh, s1bl, t + 3);
        COMPUTE(1);
        if (t + 2 < nt) WRITE_TILE(0, s0a0, s0a1, s0l0, s0l1, s0bh, s0bl);
        __syncthreads();
    }

#undef LOAD_TILE
#undef WRITE_TILE
#undef COMPUTE

    int crb = (lane >> 4) * 4;
    int cco = lane & 15;
#pragma unroll
    for (int mf = 0; mf < MF; ++mf) {
#pragma unroll
        for (int nf = 0; nf < 2; ++nf) {
            int col = col0 + nbase + nf*16 + cco;
            if (col < N) {
#pragma unroll
                for (int r = 0; r < 4; ++r) {
                    int row = row0 + mbase + mf*16 + crb + r;
                    size_t o = (size_t)row*N + col;
                    float vv = acc[mf][nf][r];
                    if (MODE == 0) Cz[o] = vv;
                    else if (MODE == 1) Cz[o] += vv;
                    else {
                        vv += bias[col];
                        Cz[o] = 0.5f * vv * (1.f + erff(vv * 0.70710678118654752f));
                    }
                }
            }
        }
    }
}

// ---------------- FUSED conv(K=4)+silu + chunk-local selective scan ----------------
// Block = (d, h, chunk). Computes silu(causal dwconv) for this block's slices
// directly from zx into LDS, then scans from LDS. Writes ys = local_scan + Dp*xs
// (D-residual folded in; no separate xs buffer). Also emits Cbuf (h==0 only,
// for pass3), cumdec, chunk-final state.
__global__ __launch_bounds__(256)
void conv_scan1(const float* __restrict__ zx, const float* __restrict__ conv_w,
                const float* __restrict__ conv_b, const float* __restrict__ dt_bias,
                const float* __restrict__ A_log, const float* __restrict__ Dp,
                float* __restrict__ ys, float* __restrict__ Cbuf,
                float* __restrict__ cstate, float* __restrict__ cumdec, int layer) {
    int bid = blockIdx.x;
    int c = bid & (NC - 1);
    int hd = bid >> NCSH;
    int d = hd >> 3, h = hd & 7;
    int tid = threadIdx.x;
    int t0 = c * QC;

    __shared__ float sxc[QC][132];   // cols 0..63 = xs slice, 64..95 = B, 96..127 = C
    __shared__ float sdt[QC];
    __shared__ float sdA[QC];

    const float* Z = zx + (size_t)d*LL*DIN;

    // ---- phase A: conv for 128 cols x 32 t ----
    {
        int col = tid & 127;
        int half = tid >> 7;            // 2 halves x 16 t
        int tstart = t0 + half*16;
        int realc = (col < 64) ? (h*PP + col) : ((col < 96) ? (DI + (col-64)) : (DI + NN + (col-96)));
        int zxcol = DI + realc;
        const float* wr = conv_w + ((size_t)(d*NL + layer)*CONV_DIM + realc)*KK;
        float w0 = wr[0], w1 = wr[1], w2 = wr[2], w3 = wr[3];
        float bias = conv_b[(size_t)(d*NL + layer)*CONV_DIM + realc];
        float z0 = (tstart-3 >= 0) ? Z[(size_t)(tstart-3)*DIN + zxcol] : 0.f;
        float z1 = (tstart-2 >= 0) ? Z[(size_t)(tstart-2)*DIN + zxcol] : 0.f;
        float z2 = (tstart-1 >= 0) ? Z[(size_t)(tstart-1)*DIN + zxcol] : 0.f;
#pragma unroll
        for (int tt = 0; tt < 16; ++tt) {
            int t = tstart + tt;
            float z3 = Z[(size_t)t*DIN + zxcol];
            float acc = bias;
            acc = fmaf(z0, w0, acc);
            acc = fmaf(z1, w1, acc);
            acc = fmaf(z2, w2, acc);
            acc = fmaf(z3, w3, acc);
            sxc[half*16 + tt][col] = siluf(acc);
            z0 = z1; z1 = z2; z2 = z3;
        }
    }
    // ---- phase A2: dt / dA for this h ----
    if (tid < QC) {
        int t = t0 + tid;
        float v = Z[(size_t)t*DIN + (DIN - HH) + h] + dt_bias[(d*NL + layer)*HH + h];
        float sp = (v > 20.f) ? v : log1pf(expf(v));
        sdt[tid] = sp;
        sdA[tid] = expf(-expf(A_log[(d*NL + layer)*HH + h]) * sp);
    }
    __syncthreads();

    // ---- phase B: chunk-local scan from LDS ----
    int p = tid >> 2, g = tid & 3, n0 = g << 3;
    float dpv = Dp[(d*NL + layer)*HH + h];
    float* ysd = ys + (size_t)d*LL*DI + h*PP + p;
    float* cdd = cumdec + (size_t)d*LL*HH + h;
    float* Cbd = Cbuf + (size_t)d*LL*NN;

    float hs[8];
#pragma unroll
    for (int j = 0; j < 8; ++j) hs[j] = 0.f;
    float cum = 1.f;

    for (int tt = 0; tt < QC; ++tt) {
        float dtv = sdt[tt], dAv = sdA[tt];
        float xv = sxc[tt][p];
        float dtx = dtv * xv;
        float4 b0 = *(const float4*)&sxc[tt][64 + n0];
        float4 b1 = *(const float4*)&sxc[tt][64 + n0 + 4];
        float4 c0 = *(const float4*)&sxc[tt][96 + n0];
        float4 c1 = *(const float4*)&sxc[tt][96 + n0 + 4];
        float B[8] = {b0.x,b0.y,b0.z,b0.w,b1.x,b1.y,b1.z,b1.w};
        float Cv[8] = {c0.x,c0.y,c0.z,c0.w,c1.x,c1.y,c1.z,c1.w};
        float acc = 0.f;
#pragma unroll
        for (int j = 0; j < 8; ++j) {
            hs[j] = fmaf(dAv, hs[j], dtx * B[j]);
            acc = fmaf(hs[j], Cv[j], acc);
        }
        acc += __shfl_xor(acc, 1);
        acc += __shfl_xor(acc, 2);
        int t = t0 + tt;
        if (g == 0) ysd[(size_t)t*DI] = acc + dpv * xv;     // D-residual folded in
        else if (g == 2 && h == 0 && p < NN) Cbd[(size_t)t*NN + p] = sxc[tt][96 + p];
        cum *= dAv;
        if (tid == 0) cdd[(size_t)t*HH] = cum;
    }

    float* cs = cstate + (((size_t)(d*NC + c)*HH + h)*PP + p)*NN + n0;
    float4 s0 = {hs[0], hs[1], hs[2], hs[3]};
    float4 s1 = {hs[4], hs[5], hs[6], hs[7]};
    *(float4*)cs = s0;
    *(float4*)(cs + 4) = s1;
}

// ---------------- pass2: sequential fixup over chunk states ----------------
__global__ __launch_bounds__(256)
void scan_pass2(float* __restrict__ cstate, const float* __restrict__ cumdec) {
    int hd = blockIdx.x;
    int d = hd >> 3, h = hd & 7;
    int tid = threadIdx.x;
    int p = tid >> 2, g = tid & 3, n0 = g << 3;
    float carry[8];
#pragma unroll
    for (int j = 0; j < 8; ++j) carry[j] = 0.f;
    for (int c = 0; c < NC; ++c) {
        float* cs = cstate + (((size_t)(d*NC + c)*HH + h)*PP + p)*NN + n0;
        float4 s0 = *(const float4*)cs;
        float4 s1 = *(const float4*)(cs + 4);
        float4 w0 = {carry[0], carry[1], carry[2], carry[3]};
        float4 w1 = {carry[4], carry[5], carry[6], carry[7]};
        *(float4*)cs = w0;
        *(float4*)(cs + 4) = w1;
        float dec = cumdec[((size_t)d*LL + (c*QC + QC - 1))*HH + h];
        float s[8] = {s0.x,s0.y,s0.z,s0.w,s1.x,s1.y,s1.z,s1.w};
#pragma unroll
        for (int j = 0; j < 8; ++j) carry[j] = fmaf(dec, carry[j], s[j]);
    }
}

// ---------------- pass3: y[t] += cumdec[t] * (C[t] . h_init) ----------------
__global__ __launch_bounds__(256)
void scan_pass3(const float* __restrict__ Cbuf, const float* __restrict__ cumdec,
                const float* __restrict__ cstate, float* __restrict__ ys) {
    int bid = blockIdx.x;
    int c = bid & (NC - 1);
    if (c == 0) return;
    int hd = bid >> NCSH;
    int d = hd >> 3, h = hd & 7;
    int tid = threadIdx.x;
    int p = tid >> 2, g = tid & 3, n0 = g << 3;
    int t0 = c * QC;

    __shared__ float scd[QC];
    if (tid < QC) scd[tid] = cumdec[((size_t)d*LL + t0 + tid)*HH + h];

    const float* cs = cstate + (((size_t)(d*NC + c)*HH + h)*PP + p)*NN + n0;
    float4 h0 = *(const float4*)cs;
    float4 h1 = *(const float4*)(cs + 4);
    float hi[8] = {h0.x,h0.y,h0.z,h0.w,h1.x,h1.y,h1.z,h1.w};
    __syncthreads();

    const float* Cbd = Cbuf + (size_t)d*LL*NN;
    float* ysd = ys + (size_t)d*LL*DI + h*PP + p;

    for (int tt = 0; tt < QC; ++tt) {
        int t = t0 + tt;
        const float* row = Cbd + (size_t)t*NN;
        float4 c0 = *(const float4*)(row + n0);
        float4 c1 = *(const float4*)(row + n0 + 4);
        float Cv[8] = {c0.x,c0.y,c0.z,c0.w,c1.x,c1.y,c1.z,c1.w};
        float acc = 0.f;
#pragma unroll
        for (int j = 0; j < 8; ++j) acc = fmaf(hi[j], Cv[j], acc);
        acc += __shfl_xor(acc, 1);
        acc += __shfl_xor(acc, 2);
        if (g == 0) ysd[(size_t)t*DI] += scd[tt] * acc;
    }
}

// ---------------- gating + RMSNorm -> bf16 hi/lo split ----------------
__global__ __launch_bounds__(256)
void gate_rms(const float* __restrict__ ys, const float* __restrict__ zx,
              const float* __restrict__ rms_g, unsigned short* __restrict__ uh,
              unsigned short* __restrict__ ul, int layer) {
    int t = blockIdx.x, d = blockIdx.y;
    const float* ysr = ys + ((size_t)d*LL + t)*DI;
    const float* zr = zx + ((size_t)d*LL + t)*DIN;
    const float* rg = rms_g + (size_t)(d*NL + layer)*DI;
    unsigned short* uhr = uh + ((size_t)d*LL + t)*DI;
    unsigned short* ulr = ul + ((size_t)d*LL + t)*DI;
    float vals[2];
    float ss = 0.f;
#pragma unroll
    for (int i = 0; i < 2; ++i) {
        int c = threadIdx.x + i*256;
        float yv = ysr[c];                 // already includes Dp*xs
        float zv = zr[c];
        float uv = yv * siluf(zv);
        vals[i] = uv;
        ss += uv * uv;
    }
    float tot = blockReduceSum256(ss);
    float scale = rsqrtf(tot / DI + 1e-5f);
#pragma unroll
    for (int i = 0; i < 2; ++i) {
        int c = threadIdx.x + i*256;
        float uv = vals[i] * scale * rg[c];
        unsigned short h = bf16_rn(uv);
        uhr[c] = h;
        ulr[c] = bf16_rn(uv - bf16_to_f(h));
    }
}

// ---------------- launch ----------------
extern "C" void kernel_launch(void* const* d_in, const int* in_sizes, int n_in,
                              void* d_out, int out_size, void* d_ws, size_t ws_size,
                              hipStream_t stream) {
    const float* vectors   = (const float*)d_in[0];
    const int*   coords    = (const int*)d_in[1];
    const float* ln_g      = (const float*)d_in[2];
    const float* ln_b      = (const float*)d_in[3];
    const float* Win       = (const float*)d_in[4];
    const float* conv_w    = (const float*)d_in[5];
    const float* conv_b    = (const float*)d_in[6];
    const float* dt_bias   = (const float*)d_in[7];
    const float* A_log     = (const float*)d_in[8];
    const float* Dp        = (const float*)d_in[9];
    const float* rms_g     = (const float*)d_in[10];
    const float* Wout      = (const float*)d_in[11];
    const float* fuse_ln_g = (const float*)d_in[12];
    const float* fuse_ln_b = (const float*)d_in[13];
    const float* fuse_W    = (const float*)d_in[14];
    const float* fuse_b    = (const float*)d_in[15];
    float* out = (float*)d_out;

    char* ws = (char*)d_ws;
    size_t off = 0;
    auto alloc = [&](size_t bytes) -> void* {
        void* p = ws + off;
        off += (bytes + 255) & ~(size_t)255;
        return p;
    };
    int* perm  = (int*)alloc((size_t)NDIR*LL*4);
    int* rank  = (int*)alloc((size_t)NDIR*LL*4);
    float* x   = (float*)alloc((size_t)NDIR*LL*DD0*4);
    unsigned short* xnh = (unsigned short*)alloc((size_t)NDIR*LL*DD0*2);
    unsigned short* xnl = (unsigned short*)alloc((size_t)NDIR*LL*DD0*2);
    float* zx  = (float*)alloc((size_t)NDIR*LL*DIN*4);
    float* Cbuf= (float*)alloc((size_t)NDIR*LL*NN*4);
    float* ysb = (float*)alloc((size_t)NDIR*LL*DI*4);
    unsigned short* uh = (unsigned short*)alloc((size_t)NDIR*LL*DI*2);
    unsigned short* ul = (unsigned short*)alloc((size_t)NDIR*LL*DI*2);
    float* cstate = (float*)alloc((size_t)NDIR*NC*HH*PP*NN*4);
    float* cumdec = (float*)alloc((size_t)NDIR*LL*HH*4);
    unsigned short* WinTh  = (unsigned short*)alloc((size_t)NDIR*NL*DIN*DD0*2);
    unsigned short* WinTl  = (unsigned short*)alloc((size_t)NDIR*NL*DIN*DD0*2);
    unsigned short* WoutTh = (unsigned short*)alloc((size_t)NDIR*NL*DD0*DI*2);
    unsigned short* WoutTl = (unsigned short*)alloc((size_t)NDIR*NL*DD0*DI*2);
    unsigned short* fWTh   = (unsigned short*)alloc((size_t)DD0*(NDIR*DD0)*2);
    unsigned short* fWTl   = (unsigned short*)alloc((size_t)DD0*(NDIR*DD0)*2);
    // mdn hi/lo aliased onto the (dead by then) uh/ul region
    unsigned short* mdnh = uh;                                // 1024*1536 shorts = 3.1MB
    unsigned short* mdnl = ul;                                // 1024*1536 shorts
    (void)ws_size;

    sort_kernel<<<NDIR, 1024, 0, stream>>>(coords, perm, rank);

    // weight transpose + split (once per launch)
    tsplit_kernel<<<dim3((DIN+31)/32, DD0/32, NDIR*NL), 256, 0, stream>>>(Win, WinTh, WinTl, DD0, DIN);
    tsplit_kernel<<<dim3(DD0/32, DI/32, NDIR*NL), 256, 0, stream>>>(Wout, WoutTh, WoutTl, DI, DD0);
    tsplit_kernel<<<dim3(DD0/32, (NDIR*DD0)/32, 1), 256, 0, stream>>>(fuse_W, fWTh, fWTl, NDIR*DD0, DD0);

    for (int l = 0; l < NL; ++l) {
        if (l == 0)
            gather_ln<<<dim3(LL, NDIR), 256, 0, stream>>>(vectors, perm, x, xnh, xnl, ln_g, ln_b);
        else
            ln_split<<<dim3(LL, NDIR), 256, 0, stream>>>(x, xnh, xnl, ln_g + l*DD0, ln_b + l*DD0,
                                                         DD0, LL, NL*DD0);
        mfma_gemm<0,64><<<dim3((DIN+63)/64, LL/64, NDIR), 256, 0, stream>>>(
            xnh, xnl, WinTh + (size_t)l*DIN*DD0, WinTl + (size_t)l*DIN*DD0, zx,
            DIN, DD0, (size_t)LL*DD0, (size_t)NL*DIN*DD0, (size_t)LL*DIN, nullptr);
        conv_scan1<<<NDIR*HH*NC, 256, 0, stream>>>(zx, conv_w, conv_b, dt_bias, A_log, Dp,
                                                   ysb, Cbuf, cstate, cumdec, l);
        scan_pass2<<<NDIR*HH, 256, 0, stream>>>(cstate, cumdec);
        scan_pass3<<<NDIR*HH*NC, 256, 0, stream>>>(Cbuf, cumdec, cstate, ysb);
        gate_rms<<<dim3(LL, NDIR), 256, 0, stream>>>(ysb, zx, rms_g, uh, ul, l);
        mfma_gemm<1,64><<<dim3(DD0/64, LL/64, NDIR), 256, 0, stream>>>(
            uh, ul, WoutTh + (size_t)l*DD0*DI, WoutTl + (size_t)l*DD0*DI, x,
            DD0, DI, (size_t)LL*DI, (size_t)NL*DD0*DI, (size_t)LL*DD0, nullptr);
    }

    ln_concat<<<LL, 256, 0, stream>>>(x, rank, mdnh, mdnl, fuse_ln_g, fuse_ln_b);
    mfma_gemm<2,64><<<dim3(DD0/64, LL/64, 1), 256, 0, stream>>>(
        mdnh, mdnl, fWTh, fWTl, out, DD0, NDIR*DD0, 0, 0, 0, fuse_b);
}